// Round 19
// baseline (242.274 us; speedup 1.0000x reference)
//
#include <hip/hip_runtime.h>

// biDAF attention: S = s1 s2^T, masked softmax over t2, U = P s2.
// B=32 (from in_sizes), t1=t2=D=1024, fp32 in/out.
//
// Round-19: r18 (best 236 us, absmax 0.039, fp16 numerics) + dead-tile
// zero-fill moved OFF gemm2's critical path: a third block class in the
// fused first dispatch writes zeros for q-tiles with row0 >= l1 (depends
// only on l1); gemm2 now returns immediately on dead tiles (no stores).
// Numeric design (measured r13-r18): QK^T = fp16 ah*bh + al*bh (2 MFMA,
// residual 2^-11); PV = Ph*Vh fp16 (1 MFMA). S partials stay fp32.
// Structure: 2-barrier reg-staged 128^2 template (at its measured ceiling
// for this masked workload; rounds 4-11: all schedule variants lost).

typedef __attribute__((ext_vector_type(8))) _Float16 f16x8;
typedef __attribute__((ext_vector_type(8))) unsigned short u16x8;
typedef __attribute__((ext_vector_type(4))) float f32x4;
typedef unsigned short u16;

constexpr int T1 = 1024;
constexpr int T2 = 1024;
constexpr int DD = 1024;
constexpr float NEGV = -1e30f;

__device__ __forceinline__ u16 f16b(float x) {          // fp32 -> fp16 (RN), bits
    union { _Float16 f; u16 u; } cv;
    cv.f = (_Float16)x;
    return cv.u;
}

__device__ __forceinline__ void splitf16(float x, u16& h, u16& l) {
    union { _Float16 f; u16 u; } cv;
    cv.f = (_Float16)x;                                  // RN hi
    h = cv.u;
    float r = x - (float)cv.f;                           // exact residual
    cv.f = (_Float16)r;
    l = cv.u;
}

__device__ __forceinline__ void splitf16x8(const float4& a, const float4& b,
                                           u16x8& h, u16x8& l) {
    u16 hh, ll;
    splitf16(a.x, hh, ll); h[0] = hh; l[0] = ll;
    splitf16(a.y, hh, ll); h[1] = hh; l[1] = ll;
    splitf16(a.z, hh, ll); h[2] = hh; l[2] = ll;
    splitf16(a.w, hh, ll); h[3] = hh; l[3] = ll;
    splitf16(b.x, hh, ll); h[4] = hh; l[4] = ll;
    splitf16(b.y, hh, ll); h[5] = hh; l[5] = ll;
    splitf16(b.z, hh, ll); h[6] = hh; l[6] = ll;
    splitf16(b.w, hh, ll); h[7] = hh; l[7] = ll;
}

__device__ __forceinline__ void cvtf16x8(const float4& a, const float4& b, u16x8& h) {
    h[0] = f16b(a.x); h[1] = f16b(a.y); h[2] = f16b(a.z); h[3] = f16b(a.w);
    h[4] = f16b(b.x); h[5] = f16b(b.y); h[6] = f16b(b.z); h[7] = f16b(b.w);
}

// ---------- fused k0+k1: gemm1 K-split | conv backfill | dead-tile zerofill ----------
__global__ __launch_bounds__(256, 2)
void gemm1_conv(const float* __restrict__ s1, const float* __restrict__ s2,
                const int* __restrict__ l1, const int* __restrict__ l2,
                float* __restrict__ SPa, float* __restrict__ SPb,
                u16* __restrict__ s2th, float* __restrict__ out,
                int ng1, int ngc)
{
    __shared__ __align__(16) u16 sBuf[3 * 128 * 40];     // 30 KB, dual-use

    int bid = (int)blockIdx.x;
    if (bid >= ng1 + ngc) {
        // ======== zero-fill path: dead output q-tiles (row0 >= l1) ========
        int zid = bid - ng1 - ngc;
        int b = zid >> 6;
        int rt = (zid >> 3) & 7, ct = zid & 7;
        int row0 = rt * 128;
        if (row0 < l1[b]) return;            // live tile: gemm2 writes it
        float* Co = out + ((size_t)b * T1 + row0) * (size_t)DD + ct * 128;
        int t = (int)threadIdx.x;
        float4 z = make_float4(0.f, 0.f, 0.f, 0.f);
        #pragma unroll
        for (int rr = 0; rr < 2; ++rr) {
            int row = (t >> 2) + rr * 64;
            #pragma unroll
            for (int ss = 0; ss < 8; ++ss)
                *(float4*)&Co[(size_t)row * DD + ((t & 3) + ss * 4) * 4] = z;
        }
        return;
    }
    if (bid >= ng1) {
        // ======== conv path: s2 -> transposed fp16-RN hi plane ========
        int cid = bid - ng1;
        int b = cid >> 8;
        int j0 = ((cid >> 4) & 15) * 64;
        int d0 = (cid & 15) * 64;
        if (j0 >= l2[b]) return;             // cols never read downstream
        float (*tile)[65] = (float(*)[65])sBuf;          // 16.6 KB < 30 KB
        int t = (int)threadIdx.x;
        const float* src = s2 + ((size_t)b * T2 + j0) * DD + d0;
        #pragma unroll
        for (int rr = 0; rr < 4; ++rr) {
            int row = (t >> 4) + rr * 16, c4 = (t & 15) * 4;
            float4 v = *(const float4*)&src[(size_t)row * DD + c4];
            tile[row][c4 + 0] = v.x; tile[row][c4 + 1] = v.y;
            tile[row][c4 + 2] = v.z; tile[row][c4 + 3] = v.w;
        }
        __syncthreads();
        #pragma unroll
        for (int rr = 0; rr < 4; ++rr) {
            int d = (t >> 4) + rr * 16, j4 = (t & 15) * 4;
            ushort4 h;
            h.x = f16b(tile[j4 + 0][d]);
            h.y = f16b(tile[j4 + 1][d]);
            h.z = f16b(tile[j4 + 2][d]);
            h.w = f16b(tile[j4 + 3][d]);
            size_t o = ((size_t)b * DD + d0 + d) * T2 + j0 + j4;
            *(ushort4*)&s2th[o] = h;
        }
        return;
    }

    // ======== gemm1 path: S = ah*bh + al*bh (fp16 RN), K-split ========
    u16* sAh = sBuf;
    u16* sAl = sBuf + 128 * 40;
    u16* sBh = sBuf + 2 * 128 * 40;

    int idx = bid;
    int batch = idx >> 7;
    int rt = (idx >> 4) & 7, ct = (idx >> 1) & 7, kp = idx & 1;
    int row0 = rt * 128, col0 = ct * 128;
    if (row0 >= l1[batch] || col0 >= l2[batch]) return;

    int t = (int)threadIdx.x;
    int lrow = t >> 2, lslot = t & 3;       // thread covers floats [lslot*8, lslot*8+8)
    int w = t >> 6, lane = t & 63, lr = lane & 15, lg = lane >> 4;
    int wr = (w >> 1) * 64, wc = (w & 1) * 64;

    const float* As = s1 + ((size_t)batch * T1 + row0) * DD + kp * 512;
    const float* Bs = s2 + ((size_t)batch * T2 + col0) * DD + kp * 512;
    float* SP = kp ? SPb : SPa;
    float* Cs = SP + ((size_t)batch * T1 + row0) * (size_t)T2 + col0;

    f32x4 acc[4][4];
    #pragma unroll
    for (int i = 0; i < 4; ++i)
        #pragma unroll
        for (int j = 0; j < 4; ++j) acc[i][j] = (f32x4)0.f;

    float4 pA[4], pB[4];                    // [rr*2+c]: floats lslot*8 + c*4 (contiguous)
    #pragma unroll
    for (int rr = 0; rr < 2; ++rr)
        #pragma unroll
        for (int c = 0; c < 2; ++c) {
            pA[rr * 2 + c] = *(const float4*)&As[(size_t)(lrow + rr * 64) * DD + lslot * 8 + c * 4];
            pB[rr * 2 + c] = *(const float4*)&Bs[(size_t)(lrow + rr * 64) * DD + lslot * 8 + c * 4];
        }

    for (int k0 = 0; k0 < 512; k0 += 32) {
        __syncthreads();
        #pragma unroll
        for (int rr = 0; rr < 2; ++rr) {
            int o = (lrow + rr * 64) * 40 + lslot * 8;   // 16B store, 16B-aligned
            u16x8 h, l;
            splitf16x8(pA[rr * 2], pA[rr * 2 + 1], h, l);
            *(u16x8*)&sAh[o] = h; *(u16x8*)&sAl[o] = l;
            cvtf16x8(pB[rr * 2], pB[rr * 2 + 1], h);
            *(u16x8*)&sBh[o] = h;
        }
        if (k0 + 32 < 512) {                 // prefetch next chunk under MFMA
            int kn = k0 + 32;
            #pragma unroll
            for (int rr = 0; rr < 2; ++rr)
                #pragma unroll
                for (int c = 0; c < 2; ++c) {
                    pA[rr * 2 + c] = *(const float4*)&As[(size_t)(lrow + rr * 64) * DD + kn + lslot * 8 + c * 4];
                    pB[rr * 2 + c] = *(const float4*)&Bs[(size_t)(lrow + rr * 64) * DD + kn + lslot * 8 + c * 4];
                }
        }
        __syncthreads();
        f16x8 ah[4], al[4];
        #pragma unroll
        for (int i = 0; i < 4; ++i) {
            int o = (wr + i * 16 + lr) * 40 + lg * 8;
            ah[i] = *(const f16x8*)&sAh[o];
            al[i] = *(const f16x8*)&sAl[o];
        }
        #pragma unroll
        for (int j = 0; j < 4; ++j) {
            int o = (wc + j * 16 + lr) * 40 + lg * 8;
            f16x8 bh = *(const f16x8*)&sBh[o];
            #pragma unroll
            for (int i = 0; i < 4; ++i) {
                acc[i][j] = __builtin_amdgcn_mfma_f32_16x16x32_f16(ah[i], bh, acc[i][j], 0, 0, 0);
                acc[i][j] = __builtin_amdgcn_mfma_f32_16x16x32_f16(al[i], bh, acc[i][j], 0, 0, 0);
            }
        }
    }
    #pragma unroll
    for (int i = 0; i < 4; ++i)
        #pragma unroll
        for (int j = 0; j < 4; ++j)
            #pragma unroll
            for (int reg = 0; reg < 4; ++reg)
                Cs[(size_t)(wr + i * 16 + 4 * lg + reg) * T2 + wc + j * 16 + lr] = acc[i][j][reg];
}

// ---------------- k2: masked softmax of (SPa [+ SPb]); P-hi (fp16) in-place ----------------
__global__ __launch_bounds__(256)
void softmax_rows(float* __restrict__ SPa, const float* __restrict__ SPb,
                  int dual, const int* __restrict__ l1, const int* __restrict__ l2)
{
    int bid = (int)blockIdx.x;
    int batch = bid >> 5;
    int row0 = (bid & 31) * 32;
    int l1v = l1[batch], l2v = l2[batch];
    if (row0 >= l1v) return;
    int w = (int)threadIdx.x >> 6, lane = (int)threadIdx.x & 63;

    for (int i = 0; i < 8; ++i) {
        int r = row0 + w * 8 + i;
        if (r >= l1v) continue;                    // wave-uniform
        size_t roff = ((size_t)batch * T1 + r) * (size_t)T2;
        float* rowa = SPa + roff;
        const float* rowb = SPb + roff;
        float x[16];
        float m = NEGV;
        #pragma unroll
        for (int s = 0; s < 4; ++s) {
            float4 va = *(const float4*)&rowa[s * 256 + lane * 4];
            if (dual) {
                float4 vb = *(const float4*)&rowb[s * 256 + lane * 4];
                va.x += vb.x; va.y += vb.y; va.z += vb.z; va.w += vb.w;
            }
            float xs[4] = {va.x, va.y, va.z, va.w};
            #pragma unroll
            for (int e = 0; e < 4; ++e) {
                int j = s * 256 + lane * 4 + e;
                float val = (j < l2v) ? xs[e] : NEGV;
                x[s * 4 + e] = val;
                m = fmaxf(m, val);
            }
        }
        #pragma unroll
        for (int off = 32; off >= 1; off >>= 1) m = fmaxf(m, __shfl_xor(m, off));
        float sum = 0.f;
        #pragma unroll
        for (int q = 0; q < 16; ++q) {
            float e = __expf(x[q] - m);            // masked -> exp(-huge)=0
            x[q] = e; sum += e;
        }
        #pragma unroll
        for (int off = 32; off >= 1; off >>= 1) sum += __shfl_xor(sum, off);
        float inv = 1.f / sum;                     // l2>=1 -> sum>=1
        u16* hi = (u16*)rowa;                      // P-hi: bytes [0,2048)
        #pragma unroll
        for (int s = 0; s < 4; ++s) {
            ushort4 h;
            h.x = f16b(x[s * 4 + 0] * inv);
            h.y = f16b(x[s * 4 + 1] * inv);
            h.z = f16b(x[s * 4 + 2] * inv);
            h.w = f16b(x[s * 4 + 3] * inv);
            *(ushort4*)&hi[s * 256 + lane * 4] = h;
        }
    }
}

// ---------------- k3: U = Ph x Vh (fp16, 1 MFMA; dead tiles pre-zeroed) ----------------
__global__ __launch_bounds__(256, 2)
void gemm2_pv(const float* __restrict__ SP, const u16* __restrict__ s2th,
              const int* __restrict__ l1, const int* __restrict__ l2,
              float* __restrict__ out)
{
    __shared__ u16 sAh[128 * 40], sBh[128 * 40];

    int idx = (int)blockIdx.x;              // natural order
    int batch = idx >> 6;
    int rt = (idx >> 3) & 7, ct = idx & 7;
    int row0 = rt * 128, col0 = ct * 128;   // q-rows, d-cols
    int l1v = l1[batch], l2v = l2[batch];
    if (row0 >= l1v) return;                // dead tile: zero-filled in dispatch 1

    int t = (int)threadIdx.x;
    float* Co = out + ((size_t)batch * T1 + row0) * (size_t)DD + col0;

    int lrow = t >> 2, lslot = t & 3;       // thread covers u16 [lslot*8, lslot*8+8)
    int w = t >> 6, lane = t & 63, lr = lane & 15, lg = lane >> 4;
    int wr = (w >> 1) * 64, wc = (w & 1) * 64;

    const u16* Pb = (const u16*)SP;         // row q: hi at q*2048
    size_t arow = ((size_t)batch * T1 + row0);
    const u16* Bh_g = s2th + ((size_t)batch * DD + col0) * (size_t)T2;

    f32x4 acc[4][4];
    #pragma unroll
    for (int i = 0; i < 4; ++i)
        #pragma unroll
        for (int j = 0; j < 4; ++j) acc[i][j] = (f32x4)0.f;

    int nk = (l2v + 31) >> 5;
    ushort4 pAh[4], pBh[4];                 // [rr*2+ss]: u16 lslot*8 + ss*4 (contiguous)
    #pragma unroll
    for (int rr = 0; rr < 2; ++rr)
        #pragma unroll
        for (int ss = 0; ss < 2; ++ss) {
            int q = lrow + rr * 64, s4 = lslot * 8 + ss * 4;
            pAh[rr * 2 + ss] = *(const ushort4*)&Pb[(arow + q) * 2048 + s4];
            pBh[rr * 2 + ss] = *(const ushort4*)&Bh_g[(size_t)q * T2 + s4];
        }

    for (int kk = 0; kk < nk; ++kk) {
        __syncthreads();
        #pragma unroll
        for (int rr = 0; rr < 2; ++rr)
            #pragma unroll
            for (int ss = 0; ss < 2; ++ss) {
                int o = (lrow + rr * 64) * 40 + lslot * 8 + ss * 4;  // adjacent 8B pair
                *(ushort4*)&sAh[o] = pAh[rr * 2 + ss];
                *(ushort4*)&sBh[o] = pBh[rr * 2 + ss];
            }
        if (kk + 1 < nk) {
            int kn = (kk + 1) * 32;
            #pragma unroll
            for (int rr = 0; rr < 2; ++rr)
                #pragma unroll
                for (int ss = 0; ss < 2; ++ss) {
                    int q = lrow + rr * 64, s4 = kn + lslot * 8 + ss * 4;
                    pAh[rr * 2 + ss] = *(const ushort4*)&Pb[(arow + q) * 2048 + s4];
                    pBh[rr * 2 + ss] = *(const ushort4*)&Bh_g[(size_t)q * T2 + s4];
                }
        }
        __syncthreads();
        f16x8 ph[4];
        #pragma unroll
        for (int i = 0; i < 4; ++i) {
            int o = (wr + i * 16 + lr) * 40 + lg * 8;
            ph[i] = *(const f16x8*)&sAh[o];
        }
        #pragma unroll
        for (int j = 0; j < 4; ++j) {
            int o = (wc + j * 16 + lr) * 40 + lg * 8;
            f16x8 vh = *(const f16x8*)&sBh[o];
            #pragma unroll
            for (int i = 0; i < 4; ++i)
                acc[i][j] = __builtin_amdgcn_mfma_f32_16x16x32_f16(ph[i], vh, acc[i][j], 0, 0, 0);
        }
    }
    #pragma unroll
    for (int i = 0; i < 4; ++i)
        #pragma unroll
        for (int reg = 0; reg < 4; ++reg) {
            int row = wr + i * 16 + 4 * lg + reg;
            bool valid = (row0 + row) < l1v;
            #pragma unroll
            for (int j = 0; j < 4; ++j)
                Co[(size_t)row * DD + wc + j * 16 + lr] = valid ? acc[i][j][reg] : 0.f;
        }
}

// ======= fallback path kernels (ws < 320 MiB; never exercised on this rig) =======
__global__ __launch_bounds__(256)
void conv_transpose(const float* __restrict__ s2, const int* __restrict__ l2,
                    u16* __restrict__ s2th)
{
    __shared__ float tile[64][65];
    int b = blockIdx.z, j0 = blockIdx.y * 64, d0 = blockIdx.x * 64;
    if (j0 >= l2[b]) return;
    int t = threadIdx.x;
    const float* src = s2 + ((size_t)b * T2 + j0) * DD + d0;
    #pragma unroll
    for (int rr = 0; rr < 4; ++rr) {
        int row = (t >> 4) + rr * 16, c4 = (t & 15) * 4;
        float4 v = *(const float4*)&src[(size_t)row * DD + c4];
        tile[row][c4 + 0] = v.x; tile[row][c4 + 1] = v.y;
        tile[row][c4 + 2] = v.z; tile[row][c4 + 3] = v.w;
    }
    __syncthreads();
    #pragma unroll
    for (int rr = 0; rr < 4; ++rr) {
        int d = (t >> 4) + rr * 16, j4 = (t & 15) * 4;
        ushort4 h;
        h.x = f16b(tile[j4 + 0][d]);
        h.y = f16b(tile[j4 + 1][d]);
        h.z = f16b(tile[j4 + 2][d]);
        h.w = f16b(tile[j4 + 3][d]);
        size_t o = ((size_t)b * DD + d0 + d) * T2 + j0 + j4;
        *(ushort4*)&s2th[o] = h;
    }
}

__global__ __launch_bounds__(256, 2)
void gemm1_qk(const float* __restrict__ s1, const int* __restrict__ l1,
              const float* __restrict__ s2, const int* __restrict__ l2,
              float* __restrict__ SP)
{
    __shared__ u16 sAh[128 * 40], sAl[128 * 40], sBh[128 * 40];

    int idx = (int)blockIdx.x;
    int batch = idx >> 6;
    int rt = (idx >> 3) & 7, ct = idx & 7;
    int row0 = rt * 128, col0 = ct * 128;
    if (row0 >= l1[batch] || col0 >= l2[batch]) return;

    int t = (int)threadIdx.x;
    int lrow = t >> 2, lslot = t & 3;
    int w = t >> 6, lane = t & 63, lr = lane & 15, lg = lane >> 4;
    int wr = (w >> 1) * 64, wc = (w & 1) * 64;

    const float* As = s1 + ((size_t)batch * T1 + row0) * DD;
    const float* Bs = s2 + ((size_t)batch * T2 + col0) * DD;
    float* Cs = SP + ((size_t)batch * T1 + row0) * (size_t)T2 + col0;

    f32x4 acc[4][4];
    #pragma unroll
    for (int i = 0; i < 4; ++i)
        #pragma unroll
        for (int j = 0; j < 4; ++j) acc[i][j] = (f32x4)0.f;

    float4 pA[4], pB[4];
    #pragma unroll
    for (int rr = 0; rr < 2; ++rr)
        #pragma unroll
        for (int c = 0; c < 2; ++c) {
            pA[rr * 2 + c] = *(const float4*)&As[(size_t)(lrow + rr * 64) * DD + lslot * 8 + c * 4];
            pB[rr * 2 + c] = *(const float4*)&Bs[(size_t)(lrow + rr * 64) * DD + lslot * 8 + c * 4];
        }

    for (int k0 = 0; k0 < DD; k0 += 32) {
        __syncthreads();
        #pragma unroll
        for (int rr = 0; rr < 2; ++rr) {
            int o = (lrow + rr * 64) * 40 + lslot * 8;
            u16x8 h, l;
            splitf16x8(pA[rr * 2], pA[rr * 2 + 1], h, l);
            *(u16x8*)&sAh[o] = h; *(u16x8*)&sAl[o] = l;
            cvtf16x8(pB[rr * 2], pB[rr * 2 + 1], h);
            *(u16x8*)&sBh[o] = h;
        }
        if (k0 + 32 < DD) {
            int kn = k0 + 32;
            #pragma unroll
            for (int rr = 0; rr < 2; ++rr)
                #pragma unroll
                for (int c = 0; c < 2; ++c) {
                    pA[rr * 2 + c] = *(const float4*)&As[(size_t)(lrow + rr * 64) * DD + kn + lslot * 8 + c * 4];
                    pB[rr * 2 + c] = *(const float4*)&Bs[(size_t)(lrow + rr * 64) * DD + kn + lslot * 8 + c * 4];
                }
        }
        __syncthreads();
        f16x8 ah[4], al[4];
        #pragma unroll
        for (int i = 0; i < 4; ++i) {
            int o = (wr + i * 16 + lr) * 40 + lg * 8;
            ah[i] = *(const f16x8*)&sAh[o];
            al[i] = *(const f16x8*)&sAl[o];
        }
        #pragma unroll
        for (int j = 0; j < 4; ++j) {
            int o = (wc + j * 16 + lr) * 40 + lg * 8;
            f16x8 bh = *(const f16x8*)&sBh[o];
            #pragma unroll
            for (int i = 0; i < 4; ++i) {
                acc[i][j] = __builtin_amdgcn_mfma_f32_16x16x32_f16(ah[i], bh, acc[i][j], 0, 0, 0);
                acc[i][j] = __builtin_amdgcn_mfma_f32_16x16x32_f16(al[i], bh, acc[i][j], 0, 0, 0);
            }
        }
    }
    #pragma unroll
    for (int i = 0; i < 4; ++i)
        #pragma unroll
        for (int j = 0; j < 4; ++j)
            #pragma unroll
            for (int reg = 0; reg < 4; ++reg)
                Cs[(size_t)(wr + i * 16 + 4 * lg + reg) * T2 + wc + j * 16 + lr] = acc[i][j][reg];
}

__global__ __launch_bounds__(256)
void zero_dead(const int* __restrict__ l1, float* __restrict__ out)
{
    int idx = (int)blockIdx.x;
    int batch = idx >> 6;
    int rt = (idx >> 3) & 7, ct = idx & 7;
    int row0 = rt * 128;
    if (row0 < l1[batch]) return;
    float* Co = out + ((size_t)batch * T1 + row0) * (size_t)DD + ct * 128;
    int t = (int)threadIdx.x;
    float4 z = make_float4(0.f, 0.f, 0.f, 0.f);
    #pragma unroll
    for (int rr = 0; rr < 2; ++rr) {
        int row = (t >> 2) + rr * 64;
        #pragma unroll
        for (int ss = 0; ss < 8; ++ss)
            *(float4*)&Co[(size_t)row * DD + ((t & 3) + ss * 4) * 4] = z;
    }
}

extern "C" void kernel_launch(void* const* d_in, const int* in_sizes, int n_in,
                              void* d_out, int out_size, void* d_ws, size_t ws_size,
                              hipStream_t stream)
{
    const float* s1 = (const float*)d_in[0];
    const int* l1 = (const int*)d_in[1];
    const float* s2 = (const float*)d_in[2];
    const int* l2 = (const int*)d_in[3];
    float* outp = (float*)d_out;

    int B = in_sizes[1];
    size_t elems = (size_t)B * T2 * DD;
    size_t sp_bytes = elems * sizeof(float);        // 128 MiB @B=32
    size_t plane = elems * sizeof(u16);             // 64 MiB

    if (ws_size >= 2 * sp_bytes + plane) {
        // main: fused {gemm1 fp16x2 K-split | conv | zerofill}, softmax, PV 1-MFMA
        char* p = (char*)d_ws;
        float* SPa = (float*)p;             p += sp_bytes;
        float* SPb = (float*)p;             p += sp_bytes;
        u16* s2th = (u16*)p;
        int ng1 = B * 128;
        int ngc = B * 256;                  // (T2/64)*(DD/64) per batch
        int ngz = B * 64;                   // output q-tiles
        gemm1_conv<<<dim3(ng1 + ngc + ngz), 256, 0, stream>>>(
            s1, s2, l1, l2, SPa, SPb, s2th, outp, ng1, ngc);
        softmax_rows<<<dim3(B * 32), 256, 0, stream>>>(SPa, SPb, 1, l1, l2);
        gemm2_pv<<<dim3(B * 64), 256, 0, stream>>>(SPa, s2th, l1, l2, outp);
    } else {
        // fallback: full-K fp16x2 gemm1, separate conv + zerofill
        float* SPa = (float*)d_ws;
        u16* s2th = (u16*)((char*)d_ws + sp_bytes);
        conv_transpose<<<dim3(DD / 64, T2 / 64, B), 256, 0, stream>>>(s2, l2, s2th);
        zero_dead<<<dim3(B * 64), 256, 0, stream>>>(l1, outp);
        gemm1_qk<<<dim3(B * 64), 256, 0, stream>>>(s1, l1, s2, l2, SPa);
        softmax_rows<<<dim3(B * 32), 256, 0, stream>>>(SPa, SPa, 0, l1, l2);
        gemm2_pv<<<dim3(B * 64), 256, 0, stream>>>(SPa, s2th, l1, l2, outp);
    }
}

// Round 20
// 233.485 us; speedup vs baseline: 1.0376x; 1.0376x over previous
//
#include <hip/hip_runtime.h>

// biDAF attention: S = s1 s2^T, masked softmax over t2, U = P s2.
// B=32 (from in_sizes), t1=t2=D=1024, fp32 in/out.
//
// Round-20: r18 (best 236 us) + dead-tile zerofill moved into the SOFTMAX
// dispatch (shortest, under-utilized) instead of dispatch 1 (r19's mistake:
// +60MB writes on the longest dispatch cost 13 us there, net -6). gemm2
// keeps early-return on dead tiles (no stores, ~750 fewer working blocks).
// Numerics (measured r13-r18): QK^T = fp16 ah*bh+al*bh (2 MFMA, res 2^-11);
// PV = Ph*Vh fp16 (1 MFMA); S partials fp32. absmax 0.0390625 vs thr 0.0994.
// Structure: 2-barrier reg-staged 128^2 template (its measured ceiling).

typedef __attribute__((ext_vector_type(8))) _Float16 f16x8;
typedef __attribute__((ext_vector_type(8))) unsigned short u16x8;
typedef __attribute__((ext_vector_type(4))) float f32x4;
typedef unsigned short u16;

constexpr int T1 = 1024;
constexpr int T2 = 1024;
constexpr int DD = 1024;
constexpr float NEGV = -1e30f;

__device__ __forceinline__ u16 f16b(float x) {          // fp32 -> fp16 (RN), bits
    union { _Float16 f; u16 u; } cv;
    cv.f = (_Float16)x;
    return cv.u;
}

__device__ __forceinline__ void splitf16(float x, u16& h, u16& l) {
    union { _Float16 f; u16 u; } cv;
    cv.f = (_Float16)x;                                  // RN hi
    h = cv.u;
    float r = x - (float)cv.f;                           // exact residual
    cv.f = (_Float16)r;
    l = cv.u;
}

__device__ __forceinline__ void splitf16x8(const float4& a, const float4& b,
                                           u16x8& h, u16x8& l) {
    u16 hh, ll;
    splitf16(a.x, hh, ll); h[0] = hh; l[0] = ll;
    splitf16(a.y, hh, ll); h[1] = hh; l[1] = ll;
    splitf16(a.z, hh, ll); h[2] = hh; l[2] = ll;
    splitf16(a.w, hh, ll); h[3] = hh; l[3] = ll;
    splitf16(b.x, hh, ll); h[4] = hh; l[4] = ll;
    splitf16(b.y, hh, ll); h[5] = hh; l[5] = ll;
    splitf16(b.z, hh, ll); h[6] = hh; l[6] = ll;
    splitf16(b.w, hh, ll); h[7] = hh; l[7] = ll;
}

__device__ __forceinline__ void cvtf16x8(const float4& a, const float4& b, u16x8& h) {
    h[0] = f16b(a.x); h[1] = f16b(a.y); h[2] = f16b(a.z); h[3] = f16b(a.w);
    h[4] = f16b(b.x); h[5] = f16b(b.y); h[6] = f16b(b.z); h[7] = f16b(b.w);
}

// ---------------- fused k0+k1: gemm1 K-split blocks, then conv backfill ----------------
__global__ __launch_bounds__(256, 2)
void gemm1_conv(const float* __restrict__ s1, const float* __restrict__ s2,
                const int* __restrict__ l1, const int* __restrict__ l2,
                float* __restrict__ SPa, float* __restrict__ SPb,
                u16* __restrict__ s2th, int ng1)
{
    __shared__ __align__(16) u16 sBuf[3 * 128 * 40];     // 30 KB, dual-use

    int bid = (int)blockIdx.x;
    if (bid >= ng1) {
        // ======== conv path: s2 -> transposed fp16-RN hi plane ========
        int cid = bid - ng1;
        int b = cid >> 8;
        int j0 = ((cid >> 4) & 15) * 64;
        int d0 = (cid & 15) * 64;
        if (j0 >= l2[b]) return;             // cols never read downstream
        float (*tile)[65] = (float(*)[65])sBuf;          // 16.6 KB < 30 KB
        int t = (int)threadIdx.x;
        const float* src = s2 + ((size_t)b * T2 + j0) * DD + d0;
        #pragma unroll
        for (int rr = 0; rr < 4; ++rr) {
            int row = (t >> 4) + rr * 16, c4 = (t & 15) * 4;
            float4 v = *(const float4*)&src[(size_t)row * DD + c4];
            tile[row][c4 + 0] = v.x; tile[row][c4 + 1] = v.y;
            tile[row][c4 + 2] = v.z; tile[row][c4 + 3] = v.w;
        }
        __syncthreads();
        #pragma unroll
        for (int rr = 0; rr < 4; ++rr) {
            int d = (t >> 4) + rr * 16, j4 = (t & 15) * 4;
            ushort4 h;
            h.x = f16b(tile[j4 + 0][d]);
            h.y = f16b(tile[j4 + 1][d]);
            h.z = f16b(tile[j4 + 2][d]);
            h.w = f16b(tile[j4 + 3][d]);
            size_t o = ((size_t)b * DD + d0 + d) * T2 + j0 + j4;
            *(ushort4*)&s2th[o] = h;
        }
        return;
    }

    // ======== gemm1 path: S = ah*bh + al*bh (fp16 RN), K-split ========
    u16* sAh = sBuf;
    u16* sAl = sBuf + 128 * 40;
    u16* sBh = sBuf + 2 * 128 * 40;

    int idx = bid;
    int batch = idx >> 7;
    int rt = (idx >> 4) & 7, ct = (idx >> 1) & 7, kp = idx & 1;
    int row0 = rt * 128, col0 = ct * 128;
    if (row0 >= l1[batch] || col0 >= l2[batch]) return;

    int t = (int)threadIdx.x;
    int lrow = t >> 2, lslot = t & 3;       // thread covers floats [lslot*8, lslot*8+8)
    int w = t >> 6, lane = t & 63, lr = lane & 15, lg = lane >> 4;
    int wr = (w >> 1) * 64, wc = (w & 1) * 64;

    const float* As = s1 + ((size_t)batch * T1 + row0) * DD + kp * 512;
    const float* Bs = s2 + ((size_t)batch * T2 + col0) * DD + kp * 512;
    float* SP = kp ? SPb : SPa;
    float* Cs = SP + ((size_t)batch * T1 + row0) * (size_t)T2 + col0;

    f32x4 acc[4][4];
    #pragma unroll
    for (int i = 0; i < 4; ++i)
        #pragma unroll
        for (int j = 0; j < 4; ++j) acc[i][j] = (f32x4)0.f;

    float4 pA[4], pB[4];                    // [rr*2+c]: floats lslot*8 + c*4 (contiguous)
    #pragma unroll
    for (int rr = 0; rr < 2; ++rr)
        #pragma unroll
        for (int c = 0; c < 2; ++c) {
            pA[rr * 2 + c] = *(const float4*)&As[(size_t)(lrow + rr * 64) * DD + lslot * 8 + c * 4];
            pB[rr * 2 + c] = *(const float4*)&Bs[(size_t)(lrow + rr * 64) * DD + lslot * 8 + c * 4];
        }

    for (int k0 = 0; k0 < 512; k0 += 32) {
        __syncthreads();
        #pragma unroll
        for (int rr = 0; rr < 2; ++rr) {
            int o = (lrow + rr * 64) * 40 + lslot * 8;   // 16B store, 16B-aligned
            u16x8 h, l;
            splitf16x8(pA[rr * 2], pA[rr * 2 + 1], h, l);
            *(u16x8*)&sAh[o] = h; *(u16x8*)&sAl[o] = l;
            cvtf16x8(pB[rr * 2], pB[rr * 2 + 1], h);
            *(u16x8*)&sBh[o] = h;
        }
        if (k0 + 32 < 512) {                 // prefetch next chunk under MFMA
            int kn = k0 + 32;
            #pragma unroll
            for (int rr = 0; rr < 2; ++rr)
                #pragma unroll
                for (int c = 0; c < 2; ++c) {
                    pA[rr * 2 + c] = *(const float4*)&As[(size_t)(lrow + rr * 64) * DD + kn + lslot * 8 + c * 4];
                    pB[rr * 2 + c] = *(const float4*)&Bs[(size_t)(lrow + rr * 64) * DD + kn + lslot * 8 + c * 4];
                }
        }
        __syncthreads();
        f16x8 ah[4], al[4];
        #pragma unroll
        for (int i = 0; i < 4; ++i) {
            int o = (wr + i * 16 + lr) * 40 + lg * 8;
            ah[i] = *(const f16x8*)&sAh[o];
            al[i] = *(const f16x8*)&sAl[o];
        }
        #pragma unroll
        for (int j = 0; j < 4; ++j) {
            int o = (wc + j * 16 + lr) * 40 + lg * 8;
            f16x8 bh = *(const f16x8*)&sBh[o];
            #pragma unroll
            for (int i = 0; i < 4; ++i) {
                acc[i][j] = __builtin_amdgcn_mfma_f32_16x16x32_f16(ah[i], bh, acc[i][j], 0, 0, 0);
                acc[i][j] = __builtin_amdgcn_mfma_f32_16x16x32_f16(al[i], bh, acc[i][j], 0, 0, 0);
            }
        }
    }
    #pragma unroll
    for (int i = 0; i < 4; ++i)
        #pragma unroll
        for (int j = 0; j < 4; ++j)
            #pragma unroll
            for (int reg = 0; reg < 4; ++reg)
                Cs[(size_t)(wr + i * 16 + 4 * lg + reg) * T2 + wc + j * 16 + lr] = acc[i][j][reg];
}

// ------- k2: masked softmax (P-hi fp16 in-place) | dead-tile zerofill backfill -------
__global__ __launch_bounds__(256)
void softmax_rows(float* __restrict__ SPa, const float* __restrict__ SPb,
                  int dual, const int* __restrict__ l1, const int* __restrict__ l2,
                  float* __restrict__ out, int ngs)
{
    int bid = (int)blockIdx.x;
    if (bid >= ngs) {
        // ======== zerofill path: dead output q-tiles (row0 >= l1) ========
        int zid = bid - ngs;
        int b = zid >> 6;
        int rt = (zid >> 3) & 7, ct = zid & 7;
        int row0 = rt * 128;
        if (row0 < l1[b]) return;            // live tile: gemm2 writes it
        float* Co = out + ((size_t)b * T1 + row0) * (size_t)DD + ct * 128;
        int t = (int)threadIdx.x;
        float4 z = make_float4(0.f, 0.f, 0.f, 0.f);
        #pragma unroll
        for (int rr = 0; rr < 2; ++rr) {
            int row = (t >> 2) + rr * 64;
            #pragma unroll
            for (int ss = 0; ss < 8; ++ss)
                *(float4*)&Co[(size_t)row * DD + ((t & 3) + ss * 4) * 4] = z;
        }
        return;
    }

    int batch = bid >> 5;
    int row0 = (bid & 31) * 32;
    int l1v = l1[batch], l2v = l2[batch];
    if (row0 >= l1v) return;
    int w = (int)threadIdx.x >> 6, lane = (int)threadIdx.x & 63;

    for (int i = 0; i < 8; ++i) {
        int r = row0 + w * 8 + i;
        if (r >= l1v) continue;                    // wave-uniform
        size_t roff = ((size_t)batch * T1 + r) * (size_t)T2;
        float* rowa = SPa + roff;
        const float* rowb = SPb + roff;
        float x[16];
        float m = NEGV;
        #pragma unroll
        for (int s = 0; s < 4; ++s) {
            float4 va = *(const float4*)&rowa[s * 256 + lane * 4];
            if (dual) {
                float4 vb = *(const float4*)&rowb[s * 256 + lane * 4];
                va.x += vb.x; va.y += vb.y; va.z += vb.z; va.w += vb.w;
            }
            float xs[4] = {va.x, va.y, va.z, va.w};
            #pragma unroll
            for (int e = 0; e < 4; ++e) {
                int j = s * 256 + lane * 4 + e;
                float val = (j < l2v) ? xs[e] : NEGV;
                x[s * 4 + e] = val;
                m = fmaxf(m, val);
            }
        }
        #pragma unroll
        for (int off = 32; off >= 1; off >>= 1) m = fmaxf(m, __shfl_xor(m, off));
        float sum = 0.f;
        #pragma unroll
        for (int q = 0; q < 16; ++q) {
            float e = __expf(x[q] - m);            // masked -> exp(-huge)=0
            x[q] = e; sum += e;
        }
        #pragma unroll
        for (int off = 32; off >= 1; off >>= 1) sum += __shfl_xor(sum, off);
        float inv = 1.f / sum;                     // l2>=1 -> sum>=1
        u16* hi = (u16*)rowa;                      // P-hi: bytes [0,2048)
        #pragma unroll
        for (int s = 0; s < 4; ++s) {
            ushort4 h;
            h.x = f16b(x[s * 4 + 0] * inv);
            h.y = f16b(x[s * 4 + 1] * inv);
            h.z = f16b(x[s * 4 + 2] * inv);
            h.w = f16b(x[s * 4 + 3] * inv);
            *(ushort4*)&hi[s * 256 + lane * 4] = h;
        }
    }
}

// ---------------- k3: U = Ph x Vh (fp16, 1 MFMA; dead tiles pre-zeroed) ----------------
__global__ __launch_bounds__(256, 2)
void gemm2_pv(const float* __restrict__ SP, const u16* __restrict__ s2th,
              const int* __restrict__ l1, const int* __restrict__ l2,
              float* __restrict__ out)
{
    __shared__ u16 sAh[128 * 40], sBh[128 * 40];

    int idx = (int)blockIdx.x;              // natural order
    int batch = idx >> 6;
    int rt = (idx >> 3) & 7, ct = idx & 7;
    int row0 = rt * 128, col0 = ct * 128;   // q-rows, d-cols
    int l1v = l1[batch], l2v = l2[batch];
    if (row0 >= l1v) return;                // dead tile: zero-filled in dispatch 2

    int t = (int)threadIdx.x;
    float* Co = out + ((size_t)batch * T1 + row0) * (size_t)DD + col0;

    int lrow = t >> 2, lslot = t & 3;       // thread covers u16 [lslot*8, lslot*8+8)
    int w = t >> 6, lane = t & 63, lr = lane & 15, lg = lane >> 4;
    int wr = (w >> 1) * 64, wc = (w & 1) * 64;

    const u16* Pb = (const u16*)SP;         // row q: hi at q*2048
    size_t arow = ((size_t)batch * T1 + row0);
    const u16* Bh_g = s2th + ((size_t)batch * DD + col0) * (size_t)T2;

    f32x4 acc[4][4];
    #pragma unroll
    for (int i = 0; i < 4; ++i)
        #pragma unroll
        for (int j = 0; j < 4; ++j) acc[i][j] = (f32x4)0.f;

    int nk = (l2v + 31) >> 5;
    ushort4 pAh[4], pBh[4];                 // [rr*2+ss]: u16 lslot*8 + ss*4 (contiguous)
    #pragma unroll
    for (int rr = 0; rr < 2; ++rr)
        #pragma unroll
        for (int ss = 0; ss < 2; ++ss) {
            int q = lrow + rr * 64, s4 = lslot * 8 + ss * 4;
            pAh[rr * 2 + ss] = *(const ushort4*)&Pb[(arow + q) * 2048 + s4];
            pBh[rr * 2 + ss] = *(const ushort4*)&Bh_g[(size_t)q * T2 + s4];
        }

    for (int kk = 0; kk < nk; ++kk) {
        __syncthreads();
        #pragma unroll
        for (int rr = 0; rr < 2; ++rr)
            #pragma unroll
            for (int ss = 0; ss < 2; ++ss) {
                int o = (lrow + rr * 64) * 40 + lslot * 8 + ss * 4;  // adjacent 8B pair
                *(ushort4*)&sAh[o] = pAh[rr * 2 + ss];
                *(ushort4*)&sBh[o] = pBh[rr * 2 + ss];
            }
        if (kk + 1 < nk) {
            int kn = (kk + 1) * 32;
            #pragma unroll
            for (int rr = 0; rr < 2; ++rr)
                #pragma unroll
                for (int ss = 0; ss < 2; ++ss) {
                    int q = lrow + rr * 64, s4 = kn + lslot * 8 + ss * 4;
                    pAh[rr * 2 + ss] = *(const ushort4*)&Pb[(arow + q) * 2048 + s4];
                    pBh[rr * 2 + ss] = *(const ushort4*)&Bh_g[(size_t)q * T2 + s4];
                }
        }
        __syncthreads();
        f16x8 ph[4];
        #pragma unroll
        for (int i = 0; i < 4; ++i) {
            int o = (wr + i * 16 + lr) * 40 + lg * 8;
            ph[i] = *(const f16x8*)&sAh[o];
        }
        #pragma unroll
        for (int j = 0; j < 4; ++j) {
            int o = (wc + j * 16 + lr) * 40 + lg * 8;
            f16x8 vh = *(const f16x8*)&sBh[o];
            #pragma unroll
            for (int i = 0; i < 4; ++i)
                acc[i][j] = __builtin_amdgcn_mfma_f32_16x16x32_f16(ph[i], vh, acc[i][j], 0, 0, 0);
        }
    }
    #pragma unroll
    for (int i = 0; i < 4; ++i)
        #pragma unroll
        for (int reg = 0; reg < 4; ++reg) {
            int row = wr + i * 16 + 4 * lg + reg;
            bool valid = (row0 + row) < l1v;
            #pragma unroll
            for (int j = 0; j < 4; ++j)
                Co[(size_t)row * DD + wc + j * 16 + lr] = valid ? acc[i][j][reg] : 0.f;
        }
}

// ======= fallback path kernels (ws < 320 MiB; never exercised on this rig) =======
__global__ __launch_bounds__(256)
void conv_transpose(const float* __restrict__ s2, const int* __restrict__ l2,
                    u16* __restrict__ s2th)
{
    __shared__ float tile[64][65];
    int b = blockIdx.z, j0 = blockIdx.y * 64, d0 = blockIdx.x * 64;
    if (j0 >= l2[b]) return;
    int t = threadIdx.x;
    const float* src = s2 + ((size_t)b * T2 + j0) * DD + d0;
    #pragma unroll
    for (int rr = 0; rr < 4; ++rr) {
        int row = (t >> 4) + rr * 16, c4 = (t & 15) * 4;
        float4 v = *(const float4*)&src[(size_t)row * DD + c4];
        tile[row][c4 + 0] = v.x; tile[row][c4 + 1] = v.y;
        tile[row][c4 + 2] = v.z; tile[row][c4 + 3] = v.w;
    }
    __syncthreads();
    #pragma unroll
    for (int rr = 0; rr < 4; ++rr) {
        int d = (t >> 4) + rr * 16, j4 = (t & 15) * 4;
        ushort4 h;
        h.x = f16b(tile[j4 + 0][d]);
        h.y = f16b(tile[j4 + 1][d]);
        h.z = f16b(tile[j4 + 2][d]);
        h.w = f16b(tile[j4 + 3][d]);
        size_t o = ((size_t)b * DD + d0 + d) * T2 + j0 + j4;
        *(ushort4*)&s2th[o] = h;
    }
}

__global__ __launch_bounds__(256, 2)
void gemm1_qk(const float* __restrict__ s1, const int* __restrict__ l1,
              const float* __restrict__ s2, const int* __restrict__ l2,
              float* __restrict__ SP)
{
    __shared__ u16 sAh[128 * 40], sAl[128 * 40], sBh[128 * 40];

    int idx = (int)blockIdx.x;
    int batch = idx >> 6;
    int rt = (idx >> 3) & 7, ct = idx & 7;
    int row0 = rt * 128, col0 = ct * 128;
    if (row0 >= l1[batch] || col0 >= l2[batch]) return;

    int t = (int)threadIdx.x;
    int lrow = t >> 2, lslot = t & 3;
    int w = t >> 6, lane = t & 63, lr = lane & 15, lg = lane >> 4;
    int wr = (w >> 1) * 64, wc = (w & 1) * 64;

    const float* As = s1 + ((size_t)batch * T1 + row0) * DD;
    const float* Bs = s2 + ((size_t)batch * T2 + col0) * DD;
    float* Cs = SP + ((size_t)batch * T1 + row0) * (size_t)T2 + col0;

    f32x4 acc[4][4];
    #pragma unroll
    for (int i = 0; i < 4; ++i)
        #pragma unroll
        for (int j = 0; j < 4; ++j) acc[i][j] = (f32x4)0.f;

    float4 pA[4], pB[4];
    #pragma unroll
    for (int rr = 0; rr < 2; ++rr)
        #pragma unroll
        for (int c = 0; c < 2; ++c) {
            pA[rr * 2 + c] = *(const float4*)&As[(size_t)(lrow + rr * 64) * DD + lslot * 8 + c * 4];
            pB[rr * 2 + c] = *(const float4*)&Bs[(size_t)(lrow + rr * 64) * DD + lslot * 8 + c * 4];
        }

    for (int k0 = 0; k0 < DD; k0 += 32) {
        __syncthreads();
        #pragma unroll
        for (int rr = 0; rr < 2; ++rr) {
            int o = (lrow + rr * 64) * 40 + lslot * 8;
            u16x8 h, l;
            splitf16x8(pA[rr * 2], pA[rr * 2 + 1], h, l);
            *(u16x8*)&sAh[o] = h; *(u16x8*)&sAl[o] = l;
            cvtf16x8(pB[rr * 2], pB[rr * 2 + 1], h);
            *(u16x8*)&sBh[o] = h;
        }
        if (k0 + 32 < DD) {
            int kn = k0 + 32;
            #pragma unroll
            for (int rr = 0; rr < 2; ++rr)
                #pragma unroll
                for (int c = 0; c < 2; ++c) {
                    pA[rr * 2 + c] = *(const float4*)&As[(size_t)(lrow + rr * 64) * DD + kn + lslot * 8 + c * 4];
                    pB[rr * 2 + c] = *(const float4*)&Bs[(size_t)(lrow + rr * 64) * DD + kn + lslot * 8 + c * 4];
                }
        }
        __syncthreads();
        f16x8 ah[4], al[4];
        #pragma unroll
        for (int i = 0; i < 4; ++i) {
            int o = (wr + i * 16 + lr) * 40 + lg * 8;
            ah[i] = *(const f16x8*)&sAh[o];
            al[i] = *(const f16x8*)&sAl[o];
        }
        #pragma unroll
        for (int j = 0; j < 4; ++j) {
            int o = (wc + j * 16 + lr) * 40 + lg * 8;
            f16x8 bh = *(const f16x8*)&sBh[o];
            #pragma unroll
            for (int i = 0; i < 4; ++i) {
                acc[i][j] = __builtin_amdgcn_mfma_f32_16x16x32_f16(ah[i], bh, acc[i][j], 0, 0, 0);
                acc[i][j] = __builtin_amdgcn_mfma_f32_16x16x32_f16(al[i], bh, acc[i][j], 0, 0, 0);
            }
        }
    }
    #pragma unroll
    for (int i = 0; i < 4; ++i)
        #pragma unroll
        for (int j = 0; j < 4; ++j)
            #pragma unroll
            for (int reg = 0; reg < 4; ++reg)
                Cs[(size_t)(wr + i * 16 + 4 * lg + reg) * T2 + wc + j * 16 + lr] = acc[i][j][reg];
}

extern "C" void kernel_launch(void* const* d_in, const int* in_sizes, int n_in,
                              void* d_out, int out_size, void* d_ws, size_t ws_size,
                              hipStream_t stream)
{
    const float* s1 = (const float*)d_in[0];
    const int* l1 = (const int*)d_in[1];
    const float* s2 = (const float*)d_in[2];
    const int* l2 = (const int*)d_in[3];
    float* outp = (float*)d_out;

    int B = in_sizes[1];
    size_t elems = (size_t)B * T2 * DD;
    size_t sp_bytes = elems * sizeof(float);        // 128 MiB @B=32
    size_t plane = elems * sizeof(u16);             // 64 MiB

    if (ws_size >= 2 * sp_bytes + plane) {
        // main: fused {gemm1 fp16x2 K-split + conv}, {softmax | zerofill}, PV 1-MFMA
        char* p = (char*)d_ws;
        float* SPa = (float*)p;             p += sp_bytes;
        float* SPb = (float*)p;             p += sp_bytes;
        u16* s2th = (u16*)p;
        int ng1 = B * 128;
        int ngc = B * 256;                  // (T2/64)*(DD/64) per batch
        int ngs = B * 32;                   // softmax row-tiles
        int ngz = B * 64;                   // output q-tiles (zerofill)
        gemm1_conv<<<dim3(ng1 + ngc), 256, 0, stream>>>(s1, s2, l1, l2, SPa, SPb, s2th, ng1);
        softmax_rows<<<dim3(ngs + ngz), 256, 0, stream>>>(SPa, SPb, 1, l1, l2, outp, ngs);
        gemm2_pv<<<dim3(B * 64), 256, 0, stream>>>(SPa, s2th, l1, l2, outp);
    } else {
        // fallback: full-K fp16x2 gemm1, separate conv; zerofill rides softmax
        float* SPa = (float*)d_ws;
        u16* s2th = (u16*)((char*)d_ws + sp_bytes);
        int ngs = B * 32, ngz = B * 64;
        conv_transpose<<<dim3(DD / 64, T2 / 64, B), 256, 0, stream>>>(s2, l2, s2th);
        gemm1_qk<<<dim3(B * 64), 256, 0, stream>>>(s1, l1, s2, l2, SPa);
        softmax_rows<<<dim3(ngs + ngz), 256, 0, stream>>>(SPa, SPa, 0, l1, l2, outp, ngs);
        gemm2_pv<<<dim3(B * 64), 256, 0, stream>>>(SPa, s2th, l1, l2, outp);
    }
}

// Round 21
// 228.691 us; speedup vs baseline: 1.0594x; 1.0210x over previous
//
#include <hip/hip_runtime.h>

// biDAF attention: S = s1 s2^T, masked softmax over t2, U = P s2.
// B=32 (from in_sizes), t1=t2=D=1024, fp32 in/out.
//
// Round-21: r20 (best 233.5 us) + softmax column-loop bounded by l2.
//  Chunks with s*256 >= l2 are pure NEGV -> exp 0 -> P 0, and gemm2 only
//  reads P columns [0, ceil32(l2)) <= ceil256(l2), so masked chunks need
//  neither reading nor writing. Wave-uniform guards on fully-unrolled
//  passes keep register indexing static (rule-#20 safe). ~45% fewer
//  softmax bytes (E[l2] ~ 512).
// Numerics (measured r13-r18): QK^T = fp16 ah*bh+al*bh (2 MFMA, res 2^-11);
// PV = Ph*Vh fp16 (1 MFMA); S partials fp32. absmax 0.0390625 vs thr 0.0994.
// Structure: 2-barrier reg-staged 128^2 template; fused {gemm1|conv},
// {softmax|zerofill}, gemm2 early-return on dead tiles.

typedef __attribute__((ext_vector_type(8))) _Float16 f16x8;
typedef __attribute__((ext_vector_type(8))) unsigned short u16x8;
typedef __attribute__((ext_vector_type(4))) float f32x4;
typedef unsigned short u16;

constexpr int T1 = 1024;
constexpr int T2 = 1024;
constexpr int DD = 1024;
constexpr float NEGV = -1e30f;

__device__ __forceinline__ u16 f16b(float x) {          // fp32 -> fp16 (RN), bits
    union { _Float16 f; u16 u; } cv;
    cv.f = (_Float16)x;
    return cv.u;
}

__device__ __forceinline__ void splitf16(float x, u16& h, u16& l) {
    union { _Float16 f; u16 u; } cv;
    cv.f = (_Float16)x;                                  // RN hi
    h = cv.u;
    float r = x - (float)cv.f;                           // exact residual
    cv.f = (_Float16)r;
    l = cv.u;
}

__device__ __forceinline__ void splitf16x8(const float4& a, const float4& b,
                                           u16x8& h, u16x8& l) {
    u16 hh, ll;
    splitf16(a.x, hh, ll); h[0] = hh; l[0] = ll;
    splitf16(a.y, hh, ll); h[1] = hh; l[1] = ll;
    splitf16(a.z, hh, ll); h[2] = hh; l[2] = ll;
    splitf16(a.w, hh, ll); h[3] = hh; l[3] = ll;
    splitf16(b.x, hh, ll); h[4] = hh; l[4] = ll;
    splitf16(b.y, hh, ll); h[5] = hh; l[5] = ll;
    splitf16(b.z, hh, ll); h[6] = hh; l[6] = ll;
    splitf16(b.w, hh, ll); h[7] = hh; l[7] = ll;
}

__device__ __forceinline__ void cvtf16x8(const float4& a, const float4& b, u16x8& h) {
    h[0] = f16b(a.x); h[1] = f16b(a.y); h[2] = f16b(a.z); h[3] = f16b(a.w);
    h[4] = f16b(b.x); h[5] = f16b(b.y); h[6] = f16b(b.z); h[7] = f16b(b.w);
}

// ---------------- fused k0+k1: gemm1 K-split blocks, then conv backfill ----------------
__global__ __launch_bounds__(256, 2)
void gemm1_conv(const float* __restrict__ s1, const float* __restrict__ s2,
                const int* __restrict__ l1, const int* __restrict__ l2,
                float* __restrict__ SPa, float* __restrict__ SPb,
                u16* __restrict__ s2th, int ng1)
{
    __shared__ __align__(16) u16 sBuf[3 * 128 * 40];     // 30 KB, dual-use

    int bid = (int)blockIdx.x;
    if (bid >= ng1) {
        // ======== conv path: s2 -> transposed fp16-RN hi plane ========
        int cid = bid - ng1;
        int b = cid >> 8;
        int j0 = ((cid >> 4) & 15) * 64;
        int d0 = (cid & 15) * 64;
        if (j0 >= l2[b]) return;             // cols never read downstream
        float (*tile)[65] = (float(*)[65])sBuf;          // 16.6 KB < 30 KB
        int t = (int)threadIdx.x;
        const float* src = s2 + ((size_t)b * T2 + j0) * DD + d0;
        #pragma unroll
        for (int rr = 0; rr < 4; ++rr) {
            int row = (t >> 4) + rr * 16, c4 = (t & 15) * 4;
            float4 v = *(const float4*)&src[(size_t)row * DD + c4];
            tile[row][c4 + 0] = v.x; tile[row][c4 + 1] = v.y;
            tile[row][c4 + 2] = v.z; tile[row][c4 + 3] = v.w;
        }
        __syncthreads();
        #pragma unroll
        for (int rr = 0; rr < 4; ++rr) {
            int d = (t >> 4) + rr * 16, j4 = (t & 15) * 4;
            ushort4 h;
            h.x = f16b(tile[j4 + 0][d]);
            h.y = f16b(tile[j4 + 1][d]);
            h.z = f16b(tile[j4 + 2][d]);
            h.w = f16b(tile[j4 + 3][d]);
            size_t o = ((size_t)b * DD + d0 + d) * T2 + j0 + j4;
            *(ushort4*)&s2th[o] = h;
        }
        return;
    }

    // ======== gemm1 path: S = ah*bh + al*bh (fp16 RN), K-split ========
    u16* sAh = sBuf;
    u16* sAl = sBuf + 128 * 40;
    u16* sBh = sBuf + 2 * 128 * 40;

    int idx = bid;
    int batch = idx >> 7;
    int rt = (idx >> 4) & 7, ct = (idx >> 1) & 7, kp = idx & 1;
    int row0 = rt * 128, col0 = ct * 128;
    if (row0 >= l1[batch] || col0 >= l2[batch]) return;

    int t = (int)threadIdx.x;
    int lrow = t >> 2, lslot = t & 3;       // thread covers floats [lslot*8, lslot*8+8)
    int w = t >> 6, lane = t & 63, lr = lane & 15, lg = lane >> 4;
    int wr = (w >> 1) * 64, wc = (w & 1) * 64;

    const float* As = s1 + ((size_t)batch * T1 + row0) * DD + kp * 512;
    const float* Bs = s2 + ((size_t)batch * T2 + col0) * DD + kp * 512;
    float* SP = kp ? SPb : SPa;
    float* Cs = SP + ((size_t)batch * T1 + row0) * (size_t)T2 + col0;

    f32x4 acc[4][4];
    #pragma unroll
    for (int i = 0; i < 4; ++i)
        #pragma unroll
        for (int j = 0; j < 4; ++j) acc[i][j] = (f32x4)0.f;

    float4 pA[4], pB[4];                    // [rr*2+c]: floats lslot*8 + c*4 (contiguous)
    #pragma unroll
    for (int rr = 0; rr < 2; ++rr)
        #pragma unroll
        for (int c = 0; c < 2; ++c) {
            pA[rr * 2 + c] = *(const float4*)&As[(size_t)(lrow + rr * 64) * DD + lslot * 8 + c * 4];
            pB[rr * 2 + c] = *(const float4*)&Bs[(size_t)(lrow + rr * 64) * DD + lslot * 8 + c * 4];
        }

    for (int k0 = 0; k0 < 512; k0 += 32) {
        __syncthreads();
        #pragma unroll
        for (int rr = 0; rr < 2; ++rr) {
            int o = (lrow + rr * 64) * 40 + lslot * 8;   // 16B store, 16B-aligned
            u16x8 h, l;
            splitf16x8(pA[rr * 2], pA[rr * 2 + 1], h, l);
            *(u16x8*)&sAh[o] = h; *(u16x8*)&sAl[o] = l;
            cvtf16x8(pB[rr * 2], pB[rr * 2 + 1], h);
            *(u16x8*)&sBh[o] = h;
        }
        if (k0 + 32 < 512) {                 // prefetch next chunk under MFMA
            int kn = k0 + 32;
            #pragma unroll
            for (int rr = 0; rr < 2; ++rr)
                #pragma unroll
                for (int c = 0; c < 2; ++c) {
                    pA[rr * 2 + c] = *(const float4*)&As[(size_t)(lrow + rr * 64) * DD + kn + lslot * 8 + c * 4];
                    pB[rr * 2 + c] = *(const float4*)&Bs[(size_t)(lrow + rr * 64) * DD + kn + lslot * 8 + c * 4];
                }
        }
        __syncthreads();
        f16x8 ah[4], al[4];
        #pragma unroll
        for (int i = 0; i < 4; ++i) {
            int o = (wr + i * 16 + lr) * 40 + lg * 8;
            ah[i] = *(const f16x8*)&sAh[o];
            al[i] = *(const f16x8*)&sAl[o];
        }
        #pragma unroll
        for (int j = 0; j < 4; ++j) {
            int o = (wc + j * 16 + lr) * 40 + lg * 8;
            f16x8 bh = *(const f16x8*)&sBh[o];
            #pragma unroll
            for (int i = 0; i < 4; ++i) {
                acc[i][j] = __builtin_amdgcn_mfma_f32_16x16x32_f16(ah[i], bh, acc[i][j], 0, 0, 0);
                acc[i][j] = __builtin_amdgcn_mfma_f32_16x16x32_f16(al[i], bh, acc[i][j], 0, 0, 0);
            }
        }
    }
    #pragma unroll
    for (int i = 0; i < 4; ++i)
        #pragma unroll
        for (int j = 0; j < 4; ++j)
            #pragma unroll
            for (int reg = 0; reg < 4; ++reg)
                Cs[(size_t)(wr + i * 16 + 4 * lg + reg) * T2 + wc + j * 16 + lr] = acc[i][j][reg];
}

// ------- k2: masked softmax (l2-bounded chunks) | dead-tile zerofill backfill -------
__global__ __launch_bounds__(256)
void softmax_rows(float* __restrict__ SPa, const float* __restrict__ SPb,
                  int dual, const int* __restrict__ l1, const int* __restrict__ l2,
                  float* __restrict__ out, int ngs)
{
    int bid = (int)blockIdx.x;
    if (bid >= ngs) {
        // ======== zerofill path: dead output q-tiles (row0 >= l1) ========
        int zid = bid - ngs;
        int b = zid >> 6;
        int rt = (zid >> 3) & 7, ct = zid & 7;
        int row0 = rt * 128;
        if (row0 < l1[b]) return;            // live tile: gemm2 writes it
        float* Co = out + ((size_t)b * T1 + row0) * (size_t)DD + ct * 128;
        int t = (int)threadIdx.x;
        float4 z = make_float4(0.f, 0.f, 0.f, 0.f);
        #pragma unroll
        for (int rr = 0; rr < 2; ++rr) {
            int row = (t >> 2) + rr * 64;
            #pragma unroll
            for (int ss = 0; ss < 8; ++ss)
                *(float4*)&Co[(size_t)row * DD + ((t & 3) + ss * 4) * 4] = z;
        }
        return;
    }

    int batch = bid >> 5;
    int row0 = (bid & 31) * 32;
    int l1v = l1[batch], l2v = l2[batch];
    if (row0 >= l1v) return;
    int w = (int)threadIdx.x >> 6, lane = (int)threadIdx.x & 63;

    for (int i = 0; i < 8; ++i) {
        int r = row0 + w * 8 + i;
        if (r >= l1v) continue;                    // wave-uniform
        size_t roff = ((size_t)batch * T1 + r) * (size_t)T2;
        float* rowa = SPa + roff;
        const float* rowb = SPb + roff;
        float x[16];
        float m = NEGV;
        #pragma unroll
        for (int s = 0; s < 4; ++s) {
            if (s * 256 < l2v) {                   // wave-uniform: skip masked chunks
                float4 va = *(const float4*)&rowa[s * 256 + lane * 4];
                if (dual) {
                    float4 vb = *(const float4*)&rowb[s * 256 + lane * 4];
                    va.x += vb.x; va.y += vb.y; va.z += vb.z; va.w += vb.w;
                }
                float xs[4] = {va.x, va.y, va.z, va.w};
                #pragma unroll
                for (int e = 0; e < 4; ++e) {
                    int j = s * 256 + lane * 4 + e;
                    float val = (j < l2v) ? xs[e] : NEGV;
                    x[s * 4 + e] = val;
                    m = fmaxf(m, val);
                }
            }
        }
        #pragma unroll
        for (int off = 32; off >= 1; off >>= 1) m = fmaxf(m, __shfl_xor(m, off));
        float sum = 0.f;
        #pragma unroll
        for (int s = 0; s < 4; ++s) {
            if (s * 256 < l2v) {
                #pragma unroll
                for (int e = 0; e < 4; ++e) {
                    float ev = __expf(x[s * 4 + e] - m);   // masked -> exp(-huge)=0
                    x[s * 4 + e] = ev;
                    sum += ev;
                }
            }
        }
        #pragma unroll
        for (int off = 32; off >= 1; off >>= 1) sum += __shfl_xor(sum, off);
        float inv = 1.f / sum;                     // l2>=1 -> sum>=1
        u16* hi = (u16*)rowa;                      // P-hi: bytes [0,2048)
        #pragma unroll
        for (int s = 0; s < 4; ++s) {
            if (s * 256 < l2v) {                   // chunks beyond never read by gemm2
                ushort4 h;
                h.x = f16b(x[s * 4 + 0] * inv);
                h.y = f16b(x[s * 4 + 1] * inv);
                h.z = f16b(x[s * 4 + 2] * inv);
                h.w = f16b(x[s * 4 + 3] * inv);
                *(ushort4*)&hi[s * 256 + lane * 4] = h;
            }
        }
    }
}

// ---------------- k3: U = Ph x Vh (fp16, 1 MFMA; dead tiles pre-zeroed) ----------------
__global__ __launch_bounds__(256, 2)
void gemm2_pv(const float* __restrict__ SP, const u16* __restrict__ s2th,
              const int* __restrict__ l1, const int* __restrict__ l2,
              float* __restrict__ out)
{
    __shared__ u16 sAh[128 * 40], sBh[128 * 40];

    int idx = (int)blockIdx.x;              // natural order
    int batch = idx >> 6;
    int rt = (idx >> 3) & 7, ct = idx & 7;
    int row0 = rt * 128, col0 = ct * 128;   // q-rows, d-cols
    int l1v = l1[batch], l2v = l2[batch];
    if (row0 >= l1v) return;                // dead tile: zero-filled in dispatch 2

    int t = (int)threadIdx.x;
    float* Co = out + ((size_t)batch * T1 + row0) * (size_t)DD + col0;

    int lrow = t >> 2, lslot = t & 3;       // thread covers u16 [lslot*8, lslot*8+8)
    int w = t >> 6, lane = t & 63, lr = lane & 15, lg = lane >> 4;
    int wr = (w >> 1) * 64, wc = (w & 1) * 64;

    const u16* Pb = (const u16*)SP;         // row q: hi at q*2048
    size_t arow = ((size_t)batch * T1 + row0);
    const u16* Bh_g = s2th + ((size_t)batch * DD + col0) * (size_t)T2;

    f32x4 acc[4][4];
    #pragma unroll
    for (int i = 0; i < 4; ++i)
        #pragma unroll
        for (int j = 0; j < 4; ++j) acc[i][j] = (f32x4)0.f;

    int nk = (l2v + 31) >> 5;
    ushort4 pAh[4], pBh[4];                 // [rr*2+ss]: u16 lslot*8 + ss*4 (contiguous)
    #pragma unroll
    for (int rr = 0; rr < 2; ++rr)
        #pragma unroll
        for (int ss = 0; ss < 2; ++ss) {
            int q = lrow + rr * 64, s4 = lslot * 8 + ss * 4;
            pAh[rr * 2 + ss] = *(const ushort4*)&Pb[(arow + q) * 2048 + s4];
            pBh[rr * 2 + ss] = *(const ushort4*)&Bh_g[(size_t)q * T2 + s4];
        }

    for (int kk = 0; kk < nk; ++kk) {
        __syncthreads();
        #pragma unroll
        for (int rr = 0; rr < 2; ++rr)
            #pragma unroll
            for (int ss = 0; ss < 2; ++ss) {
                int o = (lrow + rr * 64) * 40 + lslot * 8 + ss * 4;  // adjacent 8B pair
                *(ushort4*)&sAh[o] = pAh[rr * 2 + ss];
                *(ushort4*)&sBh[o] = pBh[rr * 2 + ss];
            }
        if (kk + 1 < nk) {
            int kn = (kk + 1) * 32;
            #pragma unroll
            for (int rr = 0; rr < 2; ++rr)
                #pragma unroll
                for (int ss = 0; ss < 2; ++ss) {
                    int q = lrow + rr * 64, s4 = kn + lslot * 8 + ss * 4;
                    pAh[rr * 2 + ss] = *(const ushort4*)&Pb[(arow + q) * 2048 + s4];
                    pBh[rr * 2 + ss] = *(const ushort4*)&Bh_g[(size_t)q * T2 + s4];
                }
        }
        __syncthreads();
        f16x8 ph[4];
        #pragma unroll
        for (int i = 0; i < 4; ++i) {
            int o = (wr + i * 16 + lr) * 40 + lg * 8;
            ph[i] = *(const f16x8*)&sAh[o];
        }
        #pragma unroll
        for (int j = 0; j < 4; ++j) {
            int o = (wc + j * 16 + lr) * 40 + lg * 8;
            f16x8 vh = *(const f16x8*)&sBh[o];
            #pragma unroll
            for (int i = 0; i < 4; ++i)
                acc[i][j] = __builtin_amdgcn_mfma_f32_16x16x32_f16(ph[i], vh, acc[i][j], 0, 0, 0);
        }
    }
    #pragma unroll
    for (int i = 0; i < 4; ++i)
        #pragma unroll
        for (int reg = 0; reg < 4; ++reg) {
            int row = wr + i * 16 + 4 * lg + reg;
            bool valid = (row0 + row) < l1v;
            #pragma unroll
            for (int j = 0; j < 4; ++j)
                Co[(size_t)row * DD + wc + j * 16 + lr] = valid ? acc[i][j][reg] : 0.f;
        }
}

// ======= fallback path kernels (ws < 320 MiB; never exercised on this rig) =======
__global__ __launch_bounds__(256)
void conv_transpose(const float* __restrict__ s2, const int* __restrict__ l2,
                    u16* __restrict__ s2th)
{
    __shared__ float tile[64][65];
    int b = blockIdx.z, j0 = blockIdx.y * 64, d0 = blockIdx.x * 64;
    if (j0 >= l2[b]) return;
    int t = threadIdx.x;
    const float* src = s2 + ((size_t)b * T2 + j0) * DD + d0;
    #pragma unroll
    for (int rr = 0; rr < 4; ++rr) {
        int row = (t >> 4) + rr * 16, c4 = (t & 15) * 4;
        float4 v = *(const float4*)&src[(size_t)row * DD + c4];
        tile[row][c4 + 0] = v.x; tile[row][c4 + 1] = v.y;
        tile[row][c4 + 2] = v.z; tile[row][c4 + 3] = v.w;
    }
    __syncthreads();
    #pragma unroll
    for (int rr = 0; rr < 4; ++rr) {
        int d = (t >> 4) + rr * 16, j4 = (t & 15) * 4;
        ushort4 h;
        h.x = f16b(tile[j4 + 0][d]);
        h.y = f16b(tile[j4 + 1][d]);
        h.z = f16b(tile[j4 + 2][d]);
        h.w = f16b(tile[j4 + 3][d]);
        size_t o = ((size_t)b * DD + d0 + d) * T2 + j0 + j4;
        *(ushort4*)&s2th[o] = h;
    }
}

__global__ __launch_bounds__(256, 2)
void gemm1_qk(const float* __restrict__ s1, const int* __restrict__ l1,
              const float* __restrict__ s2, const int* __restrict__ l2,
              float* __restrict__ SP)
{
    __shared__ u16 sAh[128 * 40], sAl[128 * 40], sBh[128 * 40];

    int idx = (int)blockIdx.x;
    int batch = idx >> 6;
    int rt = (idx >> 3) & 7, ct = idx & 7;
    int row0 = rt * 128, col0 = ct * 128;
    if (row0 >= l1[batch] || col0 >= l2[batch]) return;

    int t = (int)threadIdx.x;
    int lrow = t >> 2, lslot = t & 3;
    int w = t >> 6, lane = t & 63, lr = lane & 15, lg = lane >> 4;
    int wr = (w >> 1) * 64, wc = (w & 1) * 64;

    const float* As = s1 + ((size_t)batch * T1 + row0) * DD;
    const float* Bs = s2 + ((size_t)batch * T2 + col0) * DD;
    float* Cs = SP + ((size_t)batch * T1 + row0) * (size_t)T2 + col0;

    f32x4 acc[4][4];
    #pragma unroll
    for (int i = 0; i < 4; ++i)
        #pragma unroll
        for (int j = 0; j < 4; ++j) acc[i][j] = (f32x4)0.f;

    float4 pA[4], pB[4];
    #pragma unroll
    for (int rr = 0; rr < 2; ++rr)
        #pragma unroll
        for (int c = 0; c < 2; ++c) {
            pA[rr * 2 + c] = *(const float4*)&As[(size_t)(lrow + rr * 64) * DD + lslot * 8 + c * 4];
            pB[rr * 2 + c] = *(const float4*)&Bs[(size_t)(lrow + rr * 64) * DD + lslot * 8 + c * 4];
        }

    for (int k0 = 0; k0 < DD; k0 += 32) {
        __syncthreads();
        #pragma unroll
        for (int rr = 0; rr < 2; ++rr) {
            int o = (lrow + rr * 64) * 40 + lslot * 8;
            u16x8 h, l;
            splitf16x8(pA[rr * 2], pA[rr * 2 + 1], h, l);
            *(u16x8*)&sAh[o] = h; *(u16x8*)&sAl[o] = l;
            cvtf16x8(pB[rr * 2], pB[rr * 2 + 1], h);
            *(u16x8*)&sBh[o] = h;
        }
        if (k0 + 32 < DD) {
            int kn = k0 + 32;
            #pragma unroll
            for (int rr = 0; rr < 2; ++rr)
                #pragma unroll
                for (int c = 0; c < 2; ++c) {
                    pA[rr * 2 + c] = *(const float4*)&As[(size_t)(lrow + rr * 64) * DD + kn + lslot * 8 + c * 4];
                    pB[rr * 2 + c] = *(const float4*)&Bs[(size_t)(lrow + rr * 64) * DD + kn + lslot * 8 + c * 4];
                }
        }
        __syncthreads();
        f16x8 ah[4], al[4];
        #pragma unroll
        for (int i = 0; i < 4; ++i) {
            int o = (wr + i * 16 + lr) * 40 + lg * 8;
            ah[i] = *(const f16x8*)&sAh[o];
            al[i] = *(const f16x8*)&sAl[o];
        }
        #pragma unroll
        for (int j = 0; j < 4; ++j) {
            int o = (wc + j * 16 + lr) * 40 + lg * 8;
            f16x8 bh = *(const f16x8*)&sBh[o];
            #pragma unroll
            for (int i = 0; i < 4; ++i) {
                acc[i][j] = __builtin_amdgcn_mfma_f32_16x16x32_f16(ah[i], bh, acc[i][j], 0, 0, 0);
                acc[i][j] = __builtin_amdgcn_mfma_f32_16x16x32_f16(al[i], bh, acc[i][j], 0, 0, 0);
            }
        }
    }
    #pragma unroll
    for (int i = 0; i < 4; ++i)
        #pragma unroll
        for (int j = 0; j < 4; ++j)
            #pragma unroll
            for (int reg = 0; reg < 4; ++reg)
                Cs[(size_t)(wr + i * 16 + 4 * lg + reg) * T2 + wc + j * 16 + lr] = acc[i][j][reg];
}

extern "C" void kernel_launch(void* const* d_in, const int* in_sizes, int n_in,
                              void* d_out, int out_size, void* d_ws, size_t ws_size,
                              hipStream_t stream)
{
    const float* s1 = (const float*)d_in[0];
    const int* l1 = (const int*)d_in[1];
    const float* s2 = (const float*)d_in[2];
    const int* l2 = (const int*)d_in[3];
    float* outp = (float*)d_out;

    int B = in_sizes[1];
    size_t elems = (size_t)B * T2 * DD;
    size_t sp_bytes = elems * sizeof(float);        // 128 MiB @B=32
    size_t plane = elems * sizeof(u16);             // 64 MiB

    if (ws_size >= 2 * sp_bytes + plane) {
        // main: fused {gemm1 fp16x2 K-split + conv}, {softmax | zerofill}, PV 1-MFMA
        char* p = (char*)d_ws;
        float* SPa = (float*)p;             p += sp_bytes;
        float* SPb = (float*)p;             p += sp_bytes;
        u16* s2th = (u16*)p;
        int ng1 = B * 128;
        int ngc = B * 256;                  // (T2/64)*(DD/64) per batch
        int ngs = B * 32;                   // softmax row-tiles
        int ngz = B * 64;                   // output q-tiles (zerofill)
        gemm1_conv<<<dim3(ng1 + ngc), 256, 0, stream>>>(s1, s2, l1, l2, SPa, SPb, s2th, ng1);
        softmax_rows<<<dim3(ngs + ngz), 256, 0, stream>>>(SPa, SPb, 1, l1, l2, outp, ngs);
        gemm2_pv<<<dim3(B * 64), 256, 0, stream>>>(SPa, s2th, l1, l2, outp);
    } else {
        // fallback: full-K fp16x2 gemm1, separate conv; zerofill rides softmax
        float* SPa = (float*)d_ws;
        u16* s2th = (u16*)((char*)d_ws + sp_bytes);
        int ngs = B * 32, ngz = B * 64;
        conv_transpose<<<dim3(DD / 64, T2 / 64, B), 256, 0, stream>>>(s2, l2, s2th);
        gemm1_qk<<<dim3(B * 64), 256, 0, stream>>>(s1, l1, s2, l2, SPa);
        softmax_rows<<<dim3(ngs + ngz), 256, 0, stream>>>(SPa, SPa, 0, l1, l2, outp, ngs);
        gemm2_pv<<<dim3(B * 64), 256, 0, stream>>>(SPa, s2th, l1, l2, outp);
    }
}

// Round 22
// 225.234 us; speedup vs baseline: 1.0757x; 1.0153x over previous
//
#include <hip/hip_runtime.h>

// biDAF attention: S = s1 s2^T, masked softmax over t2, U = P s2.
// B=32 (from in_sizes), t1=t2=D=1024, fp32 in/out.
//
// Round-22: r21 (best 228.7 us, absmax 0.039) + final calibrated trim:
//  QK^T = ah*bh PURE fp16 (1 MFMA). Measured ledger: dropping the fp16
//  b-lo cross term cost +0.008 absmax (r18); the a-lo term is statistically
//  identical -> predicted +0.01, total ~0.05 vs threshold 0.0994.
//  gemm1: 1 MFMA/step-pair (was 2), 2 LDS planes (20 KB), cvt-only staging.
//  PV = Ph*Vh fp16 (1 MFMA). S partials fp32. All other kernels unchanged.
// Structure: 2-barrier reg-staged 128^2 template; fused {gemm1|conv},
// {softmax(l2-bounded)|zerofill}, gemm2 early-return on dead tiles.

typedef __attribute__((ext_vector_type(8))) _Float16 f16x8;
typedef __attribute__((ext_vector_type(8))) unsigned short u16x8;
typedef __attribute__((ext_vector_type(4))) float f32x4;
typedef unsigned short u16;

constexpr int T1 = 1024;
constexpr int T2 = 1024;
constexpr int DD = 1024;
constexpr float NEGV = -1e30f;

__device__ __forceinline__ u16 f16b(float x) {          // fp32 -> fp16 (RN), bits
    union { _Float16 f; u16 u; } cv;
    cv.f = (_Float16)x;
    return cv.u;
}

__device__ __forceinline__ void cvtf16x8(const float4& a, const float4& b, u16x8& h) {
    h[0] = f16b(a.x); h[1] = f16b(a.y); h[2] = f16b(a.z); h[3] = f16b(a.w);
    h[4] = f16b(b.x); h[5] = f16b(b.y); h[6] = f16b(b.z); h[7] = f16b(b.w);
}

// ---------------- fused k0+k1: gemm1 K-split blocks, then conv backfill ----------------
__global__ __launch_bounds__(256, 2)
void gemm1_conv(const float* __restrict__ s1, const float* __restrict__ s2,
                const int* __restrict__ l1, const int* __restrict__ l2,
                float* __restrict__ SPa, float* __restrict__ SPb,
                u16* __restrict__ s2th, int ng1)
{
    __shared__ __align__(16) u16 sBuf[2 * 128 * 40];     // 20 KB, dual-use

    int bid = (int)blockIdx.x;
    if (bid >= ng1) {
        // ======== conv path: s2 -> transposed fp16-RN hi plane ========
        int cid = bid - ng1;
        int b = cid >> 8;
        int j0 = ((cid >> 4) & 15) * 64;
        int d0 = (cid & 15) * 64;
        if (j0 >= l2[b]) return;             // cols never read downstream
        float (*tile)[65] = (float(*)[65])sBuf;          // 16.6 KB < 20 KB
        int t = (int)threadIdx.x;
        const float* src = s2 + ((size_t)b * T2 + j0) * DD + d0;
        #pragma unroll
        for (int rr = 0; rr < 4; ++rr) {
            int row = (t >> 4) + rr * 16, c4 = (t & 15) * 4;
            float4 v = *(const float4*)&src[(size_t)row * DD + c4];
            tile[row][c4 + 0] = v.x; tile[row][c4 + 1] = v.y;
            tile[row][c4 + 2] = v.z; tile[row][c4 + 3] = v.w;
        }
        __syncthreads();
        #pragma unroll
        for (int rr = 0; rr < 4; ++rr) {
            int d = (t >> 4) + rr * 16, j4 = (t & 15) * 4;
            ushort4 h;
            h.x = f16b(tile[j4 + 0][d]);
            h.y = f16b(tile[j4 + 1][d]);
            h.z = f16b(tile[j4 + 2][d]);
            h.w = f16b(tile[j4 + 3][d]);
            size_t o = ((size_t)b * DD + d0 + d) * T2 + j0 + j4;
            *(ushort4*)&s2th[o] = h;
        }
        return;
    }

    // ======== gemm1 path: S = ah*bh (pure fp16, 1 MFMA), K-split ========
    u16* sAh = sBuf;
    u16* sBh = sBuf + 128 * 40;

    int idx = bid;
    int batch = idx >> 7;
    int rt = (idx >> 4) & 7, ct = (idx >> 1) & 7, kp = idx & 1;
    int row0 = rt * 128, col0 = ct * 128;
    if (row0 >= l1[batch] || col0 >= l2[batch]) return;

    int t = (int)threadIdx.x;
    int lrow = t >> 2, lslot = t & 3;       // thread covers floats [lslot*8, lslot*8+8)
    int w = t >> 6, lane = t & 63, lr = lane & 15, lg = lane >> 4;
    int wr = (w >> 1) * 64, wc = (w & 1) * 64;

    const float* As = s1 + ((size_t)batch * T1 + row0) * DD + kp * 512;
    const float* Bs = s2 + ((size_t)batch * T2 + col0) * DD + kp * 512;
    float* SP = kp ? SPb : SPa;
    float* Cs = SP + ((size_t)batch * T1 + row0) * (size_t)T2 + col0;

    f32x4 acc[4][4];
    #pragma unroll
    for (int i = 0; i < 4; ++i)
        #pragma unroll
        for (int j = 0; j < 4; ++j) acc[i][j] = (f32x4)0.f;

    float4 pA[4], pB[4];                    // [rr*2+c]: floats lslot*8 + c*4 (contiguous)
    #pragma unroll
    for (int rr = 0; rr < 2; ++rr)
        #pragma unroll
        for (int c = 0; c < 2; ++c) {
            pA[rr * 2 + c] = *(const float4*)&As[(size_t)(lrow + rr * 64) * DD + lslot * 8 + c * 4];
            pB[rr * 2 + c] = *(const float4*)&Bs[(size_t)(lrow + rr * 64) * DD + lslot * 8 + c * 4];
        }

    for (int k0 = 0; k0 < 512; k0 += 32) {
        __syncthreads();
        #pragma unroll
        for (int rr = 0; rr < 2; ++rr) {
            int o = (lrow + rr * 64) * 40 + lslot * 8;   // 16B store, 16B-aligned
            u16x8 h;
            cvtf16x8(pA[rr * 2], pA[rr * 2 + 1], h);
            *(u16x8*)&sAh[o] = h;
            cvtf16x8(pB[rr * 2], pB[rr * 2 + 1], h);
            *(u16x8*)&sBh[o] = h;
        }
        if (k0 + 32 < 512) {                 // prefetch next chunk under MFMA
            int kn = k0 + 32;
            #pragma unroll
            for (int rr = 0; rr < 2; ++rr)
                #pragma unroll
                for (int c = 0; c < 2; ++c) {
                    pA[rr * 2 + c] = *(const float4*)&As[(size_t)(lrow + rr * 64) * DD + kn + lslot * 8 + c * 4];
                    pB[rr * 2 + c] = *(const float4*)&Bs[(size_t)(lrow + rr * 64) * DD + kn + lslot * 8 + c * 4];
                }
        }
        __syncthreads();
        f16x8 ah[4];
        #pragma unroll
        for (int i = 0; i < 4; ++i) {
            int o = (wr + i * 16 + lr) * 40 + lg * 8;
            ah[i] = *(const f16x8*)&sAh[o];
        }
        #pragma unroll
        for (int j = 0; j < 4; ++j) {
            int o = (wc + j * 16 + lr) * 40 + lg * 8;
            f16x8 bh = *(const f16x8*)&sBh[o];
            #pragma unroll
            for (int i = 0; i < 4; ++i)
                acc[i][j] = __builtin_amdgcn_mfma_f32_16x16x32_f16(ah[i], bh, acc[i][j], 0, 0, 0);
        }
    }
    #pragma unroll
    for (int i = 0; i < 4; ++i)
        #pragma unroll
        for (int j = 0; j < 4; ++j)
            #pragma unroll
            for (int reg = 0; reg < 4; ++reg)
                Cs[(size_t)(wr + i * 16 + 4 * lg + reg) * T2 + wc + j * 16 + lr] = acc[i][j][reg];
}

// ------- k2: masked softmax (l2-bounded chunks) | dead-tile zerofill backfill -------
__global__ __launch_bounds__(256)
void softmax_rows(float* __restrict__ SPa, const float* __restrict__ SPb,
                  int dual, const int* __restrict__ l1, const int* __restrict__ l2,
                  float* __restrict__ out, int ngs)
{
    int bid = (int)blockIdx.x;
    if (bid >= ngs) {
        // ======== zerofill path: dead output q-tiles (row0 >= l1) ========
        int zid = bid - ngs;
        int b = zid >> 6;
        int rt = (zid >> 3) & 7, ct = zid & 7;
        int row0 = rt * 128;
        if (row0 < l1[b]) return;            // live tile: gemm2 writes it
        float* Co = out + ((size_t)b * T1 + row0) * (size_t)DD + ct * 128;
        int t = (int)threadIdx.x;
        float4 z = make_float4(0.f, 0.f, 0.f, 0.f);
        #pragma unroll
        for (int rr = 0; rr < 2; ++rr) {
            int row = (t >> 2) + rr * 64;
            #pragma unroll
            for (int ss = 0; ss < 8; ++ss)
                *(float4*)&Co[(size_t)row * DD + ((t & 3) + ss * 4) * 4] = z;
        }
        return;
    }

    int batch = bid >> 5;
    int row0 = (bid & 31) * 32;
    int l1v = l1[batch], l2v = l2[batch];
    if (row0 >= l1v) return;
    int w = (int)threadIdx.x >> 6, lane = (int)threadIdx.x & 63;

    for (int i = 0; i < 8; ++i) {
        int r = row0 + w * 8 + i;
        if (r >= l1v) continue;                    // wave-uniform
        size_t roff = ((size_t)batch * T1 + r) * (size_t)T2;
        float* rowa = SPa + roff;
        const float* rowb = SPb + roff;
        float x[16];
        float m = NEGV;
        #pragma unroll
        for (int s = 0; s < 4; ++s) {
            if (s * 256 < l2v) {                   // wave-uniform: skip masked chunks
                float4 va = *(const float4*)&rowa[s * 256 + lane * 4];
                if (dual) {
                    float4 vb = *(const float4*)&rowb[s * 256 + lane * 4];
                    va.x += vb.x; va.y += vb.y; va.z += vb.z; va.w += vb.w;
                }
                float xs[4] = {va.x, va.y, va.z, va.w};
                #pragma unroll
                for (int e = 0; e < 4; ++e) {
                    int j = s * 256 + lane * 4 + e;
                    float val = (j < l2v) ? xs[e] : NEGV;
                    x[s * 4 + e] = val;
                    m = fmaxf(m, val);
                }
            }
        }
        #pragma unroll
        for (int off = 32; off >= 1; off >>= 1) m = fmaxf(m, __shfl_xor(m, off));
        float sum = 0.f;
        #pragma unroll
        for (int s = 0; s < 4; ++s) {
            if (s * 256 < l2v) {
                #pragma unroll
                for (int e = 0; e < 4; ++e) {
                    float ev = __expf(x[s * 4 + e] - m);   // masked -> exp(-huge)=0
                    x[s * 4 + e] = ev;
                    sum += ev;
                }
            }
        }
        #pragma unroll
        for (int off = 32; off >= 1; off >>= 1) sum += __shfl_xor(sum, off);
        float inv = 1.f / sum;                     // l2>=1 -> sum>=1
        u16* hi = (u16*)rowa;                      // P-hi: bytes [0,2048)
        #pragma unroll
        for (int s = 0; s < 4; ++s) {
            if (s * 256 < l2v) {                   // chunks beyond never read by gemm2
                ushort4 h;
                h.x = f16b(x[s * 4 + 0] * inv);
                h.y = f16b(x[s * 4 + 1] * inv);
                h.z = f16b(x[s * 4 + 2] * inv);
                h.w = f16b(x[s * 4 + 3] * inv);
                *(ushort4*)&hi[s * 256 + lane * 4] = h;
            }
        }
    }
}

// ---------------- k3: U = Ph x Vh (fp16, 1 MFMA; dead tiles pre-zeroed) ----------------
__global__ __launch_bounds__(256, 2)
void gemm2_pv(const float* __restrict__ SP, const u16* __restrict__ s2th,
              const int* __restrict__ l1, const int* __restrict__ l2,
              float* __restrict__ out)
{
    __shared__ u16 sAh[128 * 40], sBh[128 * 40];

    int idx = (int)blockIdx.x;              // natural order
    int batch = idx >> 6;
    int rt = (idx >> 3) & 7, ct = idx & 7;
    int row0 = rt * 128, col0 = ct * 128;   // q-rows, d-cols
    int l1v = l1[batch], l2v = l2[batch];
    if (row0 >= l1v) return;                // dead tile: zero-filled in dispatch 2

    int t = (int)threadIdx.x;
    float* Co = out + ((size_t)batch * T1 + row0) * (size_t)DD + col0;

    int lrow = t >> 2, lslot = t & 3;       // thread covers u16 [lslot*8, lslot*8+8)
    int w = t >> 6, lane = t & 63, lr = lane & 15, lg = lane >> 4;
    int wr = (w >> 1) * 64, wc = (w & 1) * 64;

    const u16* Pb = (const u16*)SP;         // row q: hi at q*2048
    size_t arow = ((size_t)batch * T1 + row0);
    const u16* Bh_g = s2th + ((size_t)batch * DD + col0) * (size_t)T2;

    f32x4 acc[4][4];
    #pragma unroll
    for (int i = 0; i < 4; ++i)
        #pragma unroll
        for (int j = 0; j < 4; ++j) acc[i][j] = (f32x4)0.f;

    int nk = (l2v + 31) >> 5;
    ushort4 pAh[4], pBh[4];                 // [rr*2+ss]: u16 lslot*8 + ss*4 (contiguous)
    #pragma unroll
    for (int rr = 0; rr < 2; ++rr)
        #pragma unroll
        for (int ss = 0; ss < 2; ++ss) {
            int q = lrow + rr * 64, s4 = lslot * 8 + ss * 4;
            pAh[rr * 2 + ss] = *(const ushort4*)&Pb[(arow + q) * 2048 + s4];
            pBh[rr * 2 + ss] = *(const ushort4*)&Bh_g[(size_t)q * T2 + s4];
        }

    for (int kk = 0; kk < nk; ++kk) {
        __syncthreads();
        #pragma unroll
        for (int rr = 0; rr < 2; ++rr)
            #pragma unroll
            for (int ss = 0; ss < 2; ++ss) {
                int o = (lrow + rr * 64) * 40 + lslot * 8 + ss * 4;  // adjacent 8B pair
                *(ushort4*)&sAh[o] = pAh[rr * 2 + ss];
                *(ushort4*)&sBh[o] = pBh[rr * 2 + ss];
            }
        if (kk + 1 < nk) {
            int kn = (kk + 1) * 32;
            #pragma unroll
            for (int rr = 0; rr < 2; ++rr)
                #pragma unroll
                for (int ss = 0; ss < 2; ++ss) {
                    int q = lrow + rr * 64, s4 = kn + lslot * 8 + ss * 4;
                    pAh[rr * 2 + ss] = *(const ushort4*)&Pb[(arow + q) * 2048 + s4];
                    pBh[rr * 2 + ss] = *(const ushort4*)&Bh_g[(size_t)q * T2 + s4];
                }
        }
        __syncthreads();
        f16x8 ph[4];
        #pragma unroll
        for (int i = 0; i < 4; ++i) {
            int o = (wr + i * 16 + lr) * 40 + lg * 8;
            ph[i] = *(const f16x8*)&sAh[o];
        }
        #pragma unroll
        for (int j = 0; j < 4; ++j) {
            int o = (wc + j * 16 + lr) * 40 + lg * 8;
            f16x8 vh = *(const f16x8*)&sBh[o];
            #pragma unroll
            for (int i = 0; i < 4; ++i)
                acc[i][j] = __builtin_amdgcn_mfma_f32_16x16x32_f16(ph[i], vh, acc[i][j], 0, 0, 0);
        }
    }
    #pragma unroll
    for (int i = 0; i < 4; ++i)
        #pragma unroll
        for (int reg = 0; reg < 4; ++reg) {
            int row = wr + i * 16 + 4 * lg + reg;
            bool valid = (row0 + row) < l1v;
            #pragma unroll
            for (int j = 0; j < 4; ++j)
                Co[(size_t)row * DD + wc + j * 16 + lr] = valid ? acc[i][j][reg] : 0.f;
        }
}

// ======= fallback path kernels (ws < 320 MiB; never exercised on this rig) =======
__global__ __launch_bounds__(256)
void conv_transpose(const float* __restrict__ s2, const int* __restrict__ l2,
                    u16* __restrict__ s2th)
{
    __shared__ float tile[64][65];
    int b = blockIdx.z, j0 = blockIdx.y * 64, d0 = blockIdx.x * 64;
    if (j0 >= l2[b]) return;
    int t = threadIdx.x;
    const float* src = s2 + ((size_t)b * T2 + j0) * DD + d0;
    #pragma unroll
    for (int rr = 0; rr < 4; ++rr) {
        int row = (t >> 4) + rr * 16, c4 = (t & 15) * 4;
        float4 v = *(const float4*)&src[(size_t)row * DD + c4];
        tile[row][c4 + 0] = v.x; tile[row][c4 + 1] = v.y;
        tile[row][c4 + 2] = v.z; tile[row][c4 + 3] = v.w;
    }
    __syncthreads();
    #pragma unroll
    for (int rr = 0; rr < 4; ++rr) {
        int d = (t >> 4) + rr * 16, j4 = (t & 15) * 4;
        ushort4 h;
        h.x = f16b(tile[j4 + 0][d]);
        h.y = f16b(tile[j4 + 1][d]);
        h.z = f16b(tile[j4 + 2][d]);
        h.w = f16b(tile[j4 + 3][d]);
        size_t o = ((size_t)b * DD + d0 + d) * T2 + j0 + j4;
        *(ushort4*)&s2th[o] = h;
    }
}

__global__ __launch_bounds__(256, 2)
void gemm1_qk(const float* __restrict__ s1, const int* __restrict__ l1,
              const float* __restrict__ s2, const int* __restrict__ l2,
              float* __restrict__ SP)
{
    __shared__ u16 sAh[128 * 40], sBh[128 * 40];

    int idx = (int)blockIdx.x;
    int batch = idx >> 6;
    int rt = (idx >> 3) & 7, ct = idx & 7;
    int row0 = rt * 128, col0 = ct * 128;
    if (row0 >= l1[batch] || col0 >= l2[batch]) return;

    int t = (int)threadIdx.x;
    int lrow = t >> 2, lslot = t & 3;
    int w = t >> 6, lane = t & 63, lr = lane & 15, lg = lane >> 4;
    int wr = (w >> 1) * 64, wc = (w & 1) * 64;

    const float* As = s1 + ((size_t)batch * T1 + row0) * DD;
    const float* Bs = s2 + ((size_t)batch * T2 + col0) * DD;
    float* Cs = SP + ((size_t)batch * T1 + row0) * (size_t)T2 + col0;

    f32x4 acc[4][4];
    #pragma unroll
    for (int i = 0; i < 4; ++i)
        #pragma unroll
        for (int j = 0; j < 4; ++j) acc[i][j] = (f32x4)0.f;

    float4 pA[4], pB[4];
    #pragma unroll
    for (int rr = 0; rr < 2; ++rr)
        #pragma unroll
        for (int c = 0; c < 2; ++c) {
            pA[rr * 2 + c] = *(const float4*)&As[(size_t)(lrow + rr * 64) * DD + lslot * 8 + c * 4];
            pB[rr * 2 + c] = *(const float4*)&Bs[(size_t)(lrow + rr * 64) * DD + lslot * 8 + c * 4];
        }

    for (int k0 = 0; k0 < DD; k0 += 32) {
        __syncthreads();
        #pragma unroll
        for (int rr = 0; rr < 2; ++rr) {
            int o = (lrow + rr * 64) * 40 + lslot * 8;
            u16x8 h;
            cvtf16x8(pA[rr * 2], pA[rr * 2 + 1], h);
            *(u16x8*)&sAh[o] = h;
            cvtf16x8(pB[rr * 2], pB[rr * 2 + 1], h);
            *(u16x8*)&sBh[o] = h;
        }
        if (k0 + 32 < DD) {
            int kn = k0 + 32;
            #pragma unroll
            for (int rr = 0; rr < 2; ++rr)
                #pragma unroll
                for (int c = 0; c < 2; ++c) {
                    pA[rr * 2 + c] = *(const float4*)&As[(size_t)(lrow + rr * 64) * DD + kn + lslot * 8 + c * 4];
                    pB[rr * 2 + c] = *(const float4*)&Bs[(size_t)(lrow + rr * 64) * DD + kn + lslot * 8 + c * 4];
                }
        }
        __syncthreads();
        f16x8 ah[4];
        #pragma unroll
        for (int i = 0; i < 4; ++i) {
            int o = (wr + i * 16 + lr) * 40 + lg * 8;
            ah[i] = *(const f16x8*)&sAh[o];
        }
        #pragma unroll
        for (int j = 0; j < 4; ++j) {
            int o = (wc + j * 16 + lr) * 40 + lg * 8;
            f16x8 bh = *(const f16x8*)&sBh[o];
            #pragma unroll
            for (int i = 0; i < 4; ++i)
                acc[i][j] = __builtin_amdgcn_mfma_f32_16x16x32_f16(ah[i], bh, acc[i][j], 0, 0, 0);
        }
    }
    #pragma unroll
    for (int i = 0; i < 4; ++i)
        #pragma unroll
        for (int j = 0; j < 4; ++j)
            #pragma unroll
            for (int reg = 0; reg < 4; ++reg)
                Cs[(size_t)(wr + i * 16 + 4 * lg + reg) * T2 + wc + j * 16 + lr] = acc[i][j][reg];
}

extern "C" void kernel_launch(void* const* d_in, const int* in_sizes, int n_in,
                              void* d_out, int out_size, void* d_ws, size_t ws_size,
                              hipStream_t stream)
{
    const float* s1 = (const float*)d_in[0];
    const int* l1 = (const int*)d_in[1];
    const float* s2 = (const float*)d_in[2];
    const int* l2 = (const int*)d_in[3];
    float* outp = (float*)d_out;

    int B = in_sizes[1];
    size_t elems = (size_t)B * T2 * DD;
    size_t sp_bytes = elems * sizeof(float);        // 128 MiB @B=32
    size_t plane = elems * sizeof(u16);             // 64 MiB

    if (ws_size >= 2 * sp_bytes + plane) {
        // main: fused {gemm1 fp16 K-split + conv}, {softmax | zerofill}, PV 1-MFMA
        char* p = (char*)d_ws;
        float* SPa = (float*)p;             p += sp_bytes;
        float* SPb = (float*)p;             p += sp_bytes;
        u16* s2th = (u16*)p;
        int ng1 = B * 128;
        int ngc = B * 256;                  // (T2/64)*(DD/64) per batch
        int ngs = B * 32;                   // softmax row-tiles
        int ngz = B * 64;                   // output q-tiles (zerofill)
        gemm1_conv<<<dim3(ng1 + ngc), 256, 0, stream>>>(s1, s2, l1, l2, SPa, SPb, s2th, ng1);
        softmax_rows<<<dim3(ngs + ngz), 256, 0, stream>>>(SPa, SPb, 1, l1, l2, outp, ngs);
        gemm2_pv<<<dim3(B * 64), 256, 0, stream>>>(SPa, s2th, l1, l2, outp);
    } else {
        // fallback: full-K fp16 gemm1, separate conv; zerofill rides softmax
        float* SPa = (float*)d_ws;
        u16* s2th = (u16*)((char*)d_ws + sp_bytes);
        int ngs = B * 32, ngz = B * 64;
        conv_transpose<<<dim3(DD / 64, T2 / 64, B), 256, 0, stream>>>(s2, l2, s2th);
        gemm1_qk<<<dim3(B * 64), 256, 0, stream>>>(s1, l1, s2, l2, SPa);
        softmax_rows<<<dim3(ngs + ngz), 256, 0, stream>>>(SPa, SPa, 0, l1, l2, outp, ngs);
        gemm2_pv<<<dim3(B * 64), 256, 0, stream>>>(SPa, s2th, l1, l2, outp);
    }
}